// Round 2
// baseline (967.499 us; speedup 1.0000x reference)
//
#include <hip/hip_runtime.h>

#define DI __device__ __forceinline__

typedef unsigned short u16;
typedef unsigned int u32;

DI float u2f(u32 x) { union { u32 u; float f; } v; v.u = x; return v.f; }
DI u32 f2u(float x) { union { u32 u; float f; } v; v.f = x; return v.u; }
DI float bflo(u32 w) { return u2f(w << 16); }
DI float bfhi(u32 w) { return u2f(w & 0xffff0000u); }
DI u16 f2bf(float f) {  // RNE
  u32 u = f2u(f);
  u32 r = (u + 0x7fffu + ((u >> 16) & 1u)) >> 16;
  return (u16)r;
}

DI float wsum64(float v) {
  v += __shfl_xor(v, 32);
  v += __shfl_xor(v, 16);
  v += __shfl_xor(v, 8);
  v += __shfl_xor(v, 4);
  v += __shfl_xor(v, 2);
  v += __shfl_xor(v, 1);
  return v;
}

DI float gelu_ex(float y) { return 0.5f * y * (1.0f + erff(y * 0.7071067811865476f)); }
DI float softplus_ex(float x) { return x > 0.f ? x + log1pf(expf(-x)) : log1pf(expf(x)); }

// ---------------- precompute: Lbar, Bbar ([h][p] planes), C transposed ([p][h] planes)
__global__ void k_pre(const float* __restrict__ Lam_re, const float* __restrict__ Lam_im,
                      const float* __restrict__ log_step,
                      const float* __restrict__ B_re, const float* __restrict__ B_im,
                      const float* __restrict__ C_re, const float* __restrict__ C_im,
                      float* __restrict__ wLbar, float* __restrict__ wBbr, float* __restrict__ wBbi,
                      float* __restrict__ wCtr, float* __restrict__ wCti) {
  int l = blockIdx.x;
  int p = threadIdx.x;  // 128
  int idx = l * 128 + p;
  float step = expf(log_step[idx]);
  float lre = -expf(Lam_re[idx]);
  float lim = Lam_im[idx];
  float er = expf(lre * step);
  float Lr = er * cosf(lim * step);
  float Li = er * sinf(lim * step);
  wLbar[idx * 2] = Lr;
  wLbar[idx * 2 + 1] = Li;
  float inv = 1.0f / (lre * lre + lim * lim);
  float nr = Lr - 1.0f, ni = Li;
  float qr = (nr * lre + ni * lim) * inv;  // (Lbar-1)/Lam  = (Lbar-1)*conj(Lam)/|Lam|^2
  float qi = (ni * lre - nr * lim) * inv;
  for (int h = 0; h < 64; ++h) {
    float br = B_re[idx * 64 + h], bim = B_im[idx * 64 + h];
    wBbr[(l * 64 + h) * 128 + p] = qr * br - qi * bim;
    wBbi[(l * 64 + h) * 128 + p] = qr * bim + qi * br;
    wCtr[idx * 64 + h] = C_re[(l * 64 + h) * 128 + p];  // [l][p][h]
    wCti[idx * 64 + h] = C_im[(l * 64 + h) * 128 + p];
  }
}

// ---------------- LN1 + Bu = einsum('ph,blh->blp')
__global__ __launch_bounds__(256) void k_ln_bu(
    const float* __restrict__ xin, const float* __restrict__ lnw, const float* __restrict__ lnb,
    const float* __restrict__ wBbr, const float* __restrict__ wBbi,
    float* __restrict__ fxg, float2* __restrict__ bu, int layer) {
  __shared__ float sbr[64 * 128];  // [h][p]
  __shared__ float sbi[64 * 128];
  int t = threadIdx.x, w = t >> 6, lane = t & 63;
  {
    const float* br = wBbr + (size_t)layer * 8192;
    const float* bi = wBbi + (size_t)layer * 8192;
    for (int e = t; e < 8192; e += 256) { sbr[e] = br[e]; sbi[e] = bi[e]; }
  }
  float wv = lnw[layer * 64 + lane], bv = lnb[layer * 64 + lane];
  __syncthreads();
  int row0 = blockIdx.x * 32 + w * 8;
  float fxv[8];
#pragma unroll
  for (int rr = 0; rr < 8; ++rr) {
    size_t r = row0 + rr;
    float x = xin[r * 64 + lane];
    float mu = wsum64(x) * 0.015625f;
    float d = x - mu;
    float var = wsum64(d * d) * 0.015625f;
    float fx = d * rsqrtf(var + 1e-5f) * wv + bv;
    fxv[rr] = fx;
    fxg[r * 64 + lane] = fx;
  }
  float ar0[8] = {}, ai0[8] = {}, ar1[8] = {}, ai1[8] = {};
  for (int h = 0; h < 64; ++h) {
    float b0r = sbr[h * 128 + lane], b0i = sbi[h * 128 + lane];
    float b1r = sbr[h * 128 + lane + 64], b1i = sbi[h * 128 + lane + 64];
#pragma unroll
    for (int rr = 0; rr < 8; ++rr) {
      float f = __shfl(fxv[rr], h);
      ar0[rr] = fmaf(b0r, f, ar0[rr]);
      ai0[rr] = fmaf(b0i, f, ai0[rr]);
      ar1[rr] = fmaf(b1r, f, ar1[rr]);
      ai1[rr] = fmaf(b1i, f, ai1[rr]);
    }
  }
#pragma unroll
  for (int rr = 0; rr < 8; ++rr) {
    size_t r = row0 + rr;
    bu[r * 128 + lane] = make_float2(ar0[rr], ai0[rr]);
    bu[r * 128 + lane + 64] = make_float2(ar1[rr], ai1[rr]);
  }
}

// ---------------- diagonal complex inclusive scan over L (in place)
__global__ __launch_bounds__(256) void k_scan(float2* __restrict__ bu,
                                              const float* __restrict__ wLbar, int layer) {
  int gid = blockIdx.x * 256 + threadIdx.x;  // 4096 threads
  int b = gid >> 7, p = gid & 127;
  float Lr = wLbar[(layer * 128 + p) * 2];
  float Li = wLbar[(layer * 128 + p) * 2 + 1];
  float2* ptr = bu + ((size_t)b * 512 * 128 + p);
  float xr = 0.f, xi = 0.f;
#pragma unroll 8
  for (int l = 0; l < 512; ++l) {
    float2 v = ptr[(size_t)l * 128];
    float nr = fmaf(Lr, xr, fmaf(-Li, xi, v.x));
    float ni = fmaf(Lr, xi, fmaf(Li, xr, v.y));
    xr = nr;
    xi = ni;
    ptr[(size_t)l * 128] = make_float2(xr, xi);
  }
}

// ---------------- y = 2*Re(C xs) + D*u ; x = gelu(y) + fx
__global__ __launch_bounds__(256) void k_yproj(
    const float2* __restrict__ xs, const float* __restrict__ wCtr, const float* __restrict__ wCti,
    const float* __restrict__ fxg, const float* __restrict__ Dp,
    float* __restrict__ xout, int layer) {
  __shared__ float ctr[64 * 64];       // half of p-range, [p][h]
  __shared__ float cti[64 * 64];
  __shared__ float2 xsh[4][8][64];
  int t = threadIdx.x, w = t >> 6, lane = t & 63;
  int row0 = blockIdx.x * 32 + w * 8;
  float acc[8] = {};
  for (int ph = 0; ph < 2; ++ph) {
    __syncthreads();
    {
      const float* sr = wCtr + ((size_t)layer * 128 + ph * 64) * 64;
      const float* si = wCti + ((size_t)layer * 128 + ph * 64) * 64;
      for (int e = t; e < 4096; e += 256) { ctr[e] = sr[e]; cti[e] = si[e]; }
    }
#pragma unroll
    for (int rr = 0; rr < 8; ++rr) {
      size_t r = row0 + rr;
      xsh[w][rr][lane] = xs[r * 128 + ph * 64 + lane];
    }
    __syncthreads();
    for (int p = 0; p < 64; ++p) {
      float cr = ctr[p * 64 + lane];
      float ci = cti[p * 64 + lane];
#pragma unroll
      for (int rr = 0; rr < 8; ++rr) {
        float2 xv = xsh[w][rr][p];
        acc[rr] = fmaf(cr, xv.x, fmaf(-ci, xv.y, acc[rr]));
      }
    }
  }
  float Dv = Dp[layer * 64 + lane];
#pragma unroll
  for (int rr = 0; rr < 8; ++rr) {
    size_t r = row0 + rr;
    float u = fxg[r * 64 + lane];
    float y = 2.f * acc[rr] + Dv * u;
    xout[r * 64 + lane] = gelu_ex(y) + u;
  }
}

// ---------------- LN2 + GLU FFN + residual (in place on x)
__global__ __launch_bounds__(256) void k_ff(
    float* __restrict__ xio, const float* __restrict__ lnw, const float* __restrict__ lnb,
    const float* __restrict__ encw, const float* __restrict__ decw, int layer) {
  __shared__ float enc[64 * 128];  // [h][j]
  __shared__ float dec[64 * 64];   // [j][h]
  int t = threadIdx.x, w = t >> 6, lane = t & 63;
  {
    const float* e = encw + (size_t)layer * 8192;
    for (int i = t; i < 8192; i += 256) enc[i] = e[i];
    const float* d = decw + (size_t)layer * 4096;
    for (int i = t; i < 4096; i += 256) dec[i] = d[i];
  }
  float wv = lnw[layer * 64 + lane], bv = lnb[layer * 64 + lane];
  __syncthreads();
  int row0 = blockIdx.x * 32 + w * 8;
  float fx2v[8];
#pragma unroll
  for (int rr = 0; rr < 8; ++rr) {
    size_t r = row0 + rr;
    float x = xio[r * 64 + lane];
    float mu = wsum64(x) * 0.015625f;
    float d = x - mu;
    float var = wsum64(d * d) * 0.015625f;
    fx2v[rr] = d * rsqrtf(var + 1e-5f) * wv + bv;
  }
  float h0[8] = {}, h1v[8] = {};
  for (int h = 0; h < 64; ++h) {
    float e0 = enc[h * 128 + lane], e1 = enc[h * 128 + lane + 64];
#pragma unroll
    for (int rr = 0; rr < 8; ++rr) {
      float f = __shfl(fx2v[rr], h);
      h0[rr] = fmaf(e0, f, h0[rr]);
      h1v[rr] = fmaf(e1, f, h1v[rr]);
    }
  }
  float gv[8];
#pragma unroll
  for (int rr = 0; rr < 8; ++rr) gv[rr] = h0[rr] * gelu_ex(h1v[rr]);
  float o[8] = {};
  for (int j = 0; j < 64; ++j) {
    float dv = dec[j * 64 + lane];
#pragma unroll
    for (int rr = 0; rr < 8; ++rr) {
      float gj = __shfl(gv[rr], j);
      o[rr] = fmaf(dv, gj, o[rr]);
    }
  }
#pragma unroll
  for (int rr = 0; rr < 8; ++rr) {
    size_t r = row0 + rr;
    xio[r * 64 + lane] = o[rr] + fx2v[rr];
  }
}

// ---------------- h1 = softplus(x @ toA_w1 + b1)
__global__ __launch_bounds__(256) void k_toa1(
    const float* __restrict__ xin, const float* __restrict__ w1, const float* __restrict__ b1,
    float* __restrict__ h1out) {
  __shared__ float w1s[64 * 128];
  int t = threadIdx.x, w = t >> 6, lane = t & 63;
  for (int i = t; i < 8192; i += 256) w1s[i] = w1[i];
  float bb0 = b1[lane], bb1 = b1[lane + 64];
  __syncthreads();
  int row0 = blockIdx.x * 32 + w * 8;
  float xv[8];
#pragma unroll
  for (int rr = 0; rr < 8; ++rr) xv[rr] = xin[(size_t)(row0 + rr) * 64 + lane];
  float a0[8] = {}, a1[8] = {};
  for (int h = 0; h < 64; ++h) {
    float e0 = w1s[h * 128 + lane], e1 = w1s[h * 128 + lane + 64];
#pragma unroll
    for (int rr = 0; rr < 8; ++rr) {
      float f = __shfl(xv[rr], h);
      a0[rr] = fmaf(e0, f, a0[rr]);
      a1[rr] = fmaf(e1, f, a1[rr]);
    }
  }
#pragma unroll
  for (int rr = 0; rr < 8; ++rr) {
    size_t r = row0 + rr;
    h1out[r * 128 + lane] = softplus_ex(a0[rr] + bb0);
    h1out[r * 128 + lane + 64] = softplus_ex(a1[rr] + bb1);
  }
}

// ---------------- big GEMM: X = 0.5*dt*(h1 @ w2 + b2)*mask  -> bf16
__global__ __launch_bounds__(256) void k_gemm(
    const float* __restrict__ h1, const float* __restrict__ w2, const float* __restrict__ b2,
    const float* __restrict__ mask, const float* __restrict__ dt, u16* __restrict__ Xout) {
  __shared__ float Ash[64][128];  // [k][m]
  __shared__ float Bsh[64][128];  // [k][n]
  int t = threadIdx.x;
  int mblk = blockIdx.y * 128, nblk = blockIdx.x * 128;
  int tx = t & 15, ty = t >> 4;
  float acc[8][8] = {{}};
  for (int kp = 0; kp < 2; ++kp) {
    __syncthreads();
    {
      int ml = t >> 1, kh = (t & 1) * 32;
      const float* src = &h1[(size_t)(mblk + ml) * 128 + kp * 64 + kh];
#pragma unroll
      for (int j4 = 0; j4 < 32; j4 += 4) {
        float4 v = *(const float4*)&src[j4];
        Ash[kh + j4 + 0][ml] = v.x;
        Ash[kh + j4 + 1][ml] = v.y;
        Ash[kh + j4 + 2][ml] = v.z;
        Ash[kh + j4 + 3][ml] = v.w;
      }
      for (int e = t; e < 2048; e += 256) {
        int k = e >> 5, n4 = (e & 31) * 4;
        *(float4*)&Bsh[k][n4] = *(const float4*)&w2[(size_t)(kp * 64 + k) * 4096 + nblk + n4];
      }
    }
    __syncthreads();
    for (int k = 0; k < 64; ++k) {
      float a[8], b[8];
      *(float4*)&a[0] = *(const float4*)&Ash[k][ty * 8];
      *(float4*)&a[4] = *(const float4*)&Ash[k][ty * 8 + 4];
      *(float4*)&b[0] = *(const float4*)&Bsh[k][tx * 8];
      *(float4*)&b[4] = *(const float4*)&Bsh[k][tx * 8 + 4];
#pragma unroll
      for (int i = 0; i < 8; ++i)
#pragma unroll
        for (int j = 0; j < 8; ++j) acc[i][j] = fmaf(a[i], b[j], acc[i][j]);
    }
  }
#pragma unroll
  for (int i = 0; i < 8; ++i) {
    int m = mblk + ty * 8 + i;
    float dv = 0.5f * dt[m];
    u32 pk[4];
#pragma unroll
    for (int jp = 0; jp < 4; ++jp) {
      int n0 = nblk + tx * 8 + jp * 2;
      float x0 = dv * (acc[i][jp * 2] + b2[n0]) * mask[n0];
      float x1 = dv * (acc[i][jp * 2 + 1] + b2[n0 + 1]) * mask[n0 + 1];
      pk[jp] = (u32)f2bf(x0) | ((u32)f2bf(x1) << 16);
    }
    *(uint4*)&Xout[(size_t)m * 4096 + nblk + tx * 8] = make_uint4(pk[0], pk[1], pk[2], pk[3]);
  }
}

// ---------------- per-system Cayley via Neumann: E = A_bar - I = 2(X + X^2 + X^3), in place
__global__ __launch_bounds__(256) void k_neumann(u16* __restrict__ Xg) {
  __shared__ float Xs[64 * 65];
  __shared__ float X2s[64 * 65];
  int t = threadIdx.x;
  u16* Xp = Xg + (size_t)blockIdx.x * 4096;
#pragma unroll
  for (int ii = 0; ii < 8; ++ii) {
    int f = ii * 256 + t;  // dword index, 2048 dwords
    u32 wv = ((const u32*)Xp)[f];
    int r = f >> 5, c = (f & 31) << 1;
    Xs[r * 65 + c] = bflo(wv);
    Xs[r * 65 + c + 1] = bfhi(wv);
  }
  __syncthreads();
  int tr = t >> 4, tc = t & 15;  // 16x16 grid of 4x4 tiles
  float acc[4][4] = {{}};
  for (int k = 0; k < 64; ++k) {
    float a4[4], b4[4];
#pragma unroll
    for (int q = 0; q < 4; ++q) a4[q] = Xs[(tr * 4 + q) * 65 + k];
#pragma unroll
    for (int p = 0; p < 4; ++p) b4[p] = Xs[k * 65 + tc * 4 + p];
#pragma unroll
    for (int q = 0; q < 4; ++q)
#pragma unroll
      for (int p = 0; p < 4; ++p) acc[q][p] = fmaf(a4[q], b4[p], acc[q][p]);
  }
#pragma unroll
  for (int q = 0; q < 4; ++q)
#pragma unroll
    for (int p = 0; p < 4; ++p) X2s[(tr * 4 + q) * 65 + tc * 4 + p] = acc[q][p];
  __syncthreads();
  float acc2[4][4] = {{}};
  for (int k = 0; k < 64; ++k) {
    float a4[4], b4[4];
#pragma unroll
    for (int q = 0; q < 4; ++q) a4[q] = Xs[(tr * 4 + q) * 65 + k];
#pragma unroll
    for (int p = 0; p < 4; ++p) b4[p] = X2s[k * 65 + tc * 4 + p];
#pragma unroll
    for (int q = 0; q < 4; ++q)
#pragma unroll
      for (int p = 0; p < 4; ++p) acc2[q][p] = fmaf(a4[q], b4[p], acc2[q][p]);
  }
#pragma unroll
  for (int q = 0; q < 4; ++q) {
    int r = tr * 4 + q;
    float e0 = 2.f * (Xs[r * 65 + tc * 4 + 0] + X2s[r * 65 + tc * 4 + 0] + acc2[q][0]);
    float e1 = 2.f * (Xs[r * 65 + tc * 4 + 1] + X2s[r * 65 + tc * 4 + 1] + acc2[q][1]);
    float e2 = 2.f * (Xs[r * 65 + tc * 4 + 2] + X2s[r * 65 + tc * 4 + 2] + acc2[q][2]);
    float e3 = 2.f * (Xs[r * 65 + tc * 4 + 3] + X2s[r * 65 + tc * 4 + 3] + acc2[q][3]);
    u32 pk0 = (u32)f2bf(e0) | ((u32)f2bf(e1) << 16);
    u32 pk1 = (u32)f2bf(e2) | ((u32)f2bf(e3) << 16);
    *(uint2*)&Xp[(size_t)r * 64 + tc * 4] = make_uint2(pk0, pk1);
  }
}

// ---------------- sequential trajectory: z_t = z_{t-1} + E[t-1] z_{t-1}  (f32 output!)
__global__ __launch_bounds__(512) void k_traj(const float* __restrict__ zin,
                                              const u16* __restrict__ E,
                                              float* __restrict__ out) {
  int b = blockIdx.x, t = threadIdx.x;
  int i = t >> 3, g = t & 7;  // row i, 8 col-groups of 8
  __shared__ float zsh[2][64];
  if (t < 64) {
    float z0 = zin[(size_t)b * 512 * 64 + t];
    zsh[0][t] = z0;
    out[(size_t)b * 512 * 64 + t] = z0;
  }
  __syncthreads();
  const u16* Eb = E + (size_t)b * 512 * 4096 + i * 64 + g * 8;
  uint4 pf0 = *(const uint4*)(Eb + 0 * 4096);
  uint4 pf1 = *(const uint4*)(Eb + 1 * 4096);
  uint4 pf2 = *(const uint4*)(Eb + 2 * 4096);
  uint4 pf3 = *(const uint4*)(Eb + 3 * 4096);
  int cur = 0;
  for (int s0 = 1; s0 <= 509; s0 += 4) {
#pragma unroll
    for (int k = 0; k < 4; ++k) {
      int s = s0 + k;
      if (s > 511) break;
      uint4 mine = (k == 0) ? pf0 : (k == 1) ? pf1 : (k == 2) ? pf2 : pf3;
      if (s + 4 <= 511) {
        uint4 nv = *(const uint4*)(Eb + (size_t)(s + 3) * 4096);
        if (k == 0) pf0 = nv;
        else if (k == 1) pf1 = nv;
        else if (k == 2) pf2 = nv;
        else pf3 = nv;
      }
      const float* zb = &zsh[cur][g * 8];
      float a = bflo(mine.x) * zb[0];
      a = fmaf(bfhi(mine.x), zb[1], a);
      a = fmaf(bflo(mine.y), zb[2], a);
      a = fmaf(bfhi(mine.y), zb[3], a);
      a = fmaf(bflo(mine.z), zb[4], a);
      a = fmaf(bfhi(mine.z), zb[5], a);
      a = fmaf(bflo(mine.w), zb[6], a);
      a = fmaf(bfhi(mine.w), zb[7], a);
      a += __shfl_xor(a, 1);
      a += __shfl_xor(a, 2);
      a += __shfl_xor(a, 4);
      if (g == 0) {
        float zi = a + zsh[cur][i];
        zsh[cur ^ 1][i] = zi;
        out[((size_t)b * 512 + s) * 64 + i] = zi;
      }
      __syncthreads();
      cur ^= 1;
    }
  }
}

extern "C" void kernel_launch(void* const* d_in, const int* in_sizes, int n_in,
                              void* d_out, int out_size, void* d_ws, size_t ws_size,
                              hipStream_t stream) {
  const float* z_input  = (const float*)d_in[0];
  const float* dt       = (const float*)d_in[1];
  const float* ln1_w    = (const float*)d_in[2];
  const float* ln1_b    = (const float*)d_in[3];
  const float* Lam_re   = (const float*)d_in[4];
  const float* Lam_im   = (const float*)d_in[5];
  const float* B_re     = (const float*)d_in[6];
  const float* B_im     = (const float*)d_in[7];
  const float* C_re     = (const float*)d_in[8];
  const float* C_im     = (const float*)d_in[9];
  const float* Dp       = (const float*)d_in[10];
  const float* log_step = (const float*)d_in[11];
  const float* ln2_w    = (const float*)d_in[12];
  const float* ln2_b    = (const float*)d_in[13];
  const float* ff_enc   = (const float*)d_in[14];
  const float* ff_dec   = (const float*)d_in[15];
  const float* toA_w1   = (const float*)d_in[16];
  const float* toA_b1   = (const float*)d_in[17];
  const float* toA_w2   = (const float*)d_in[18];
  const float* toA_b2   = (const float*)d_in[19];
  const float* mask_A   = (const float*)d_in[20];

  char* ws = (char*)d_ws;
  float* wLbar = (float*)(ws + 0);
  float* wBbr  = (float*)(ws + 2048);
  float* wBbi  = (float*)(ws + 67584);
  float* wCtr  = (float*)(ws + 133120);
  float* wCti  = (float*)(ws + 198656);
  float* wfx   = (float*)(ws + 264192);
  float* wx    = (float*)(ws + 4458496);
  float2* wbu  = (float2*)(ws + 8652800);
  float* wh1   = (float*)(ws + 25430016);
  u16* wX      = (u16*)(ws + 33818624);
  if (ws_size < 168036352ull) return;  // would corrupt memory otherwise

  k_pre<<<2, 128, 0, stream>>>(Lam_re, Lam_im, log_step, B_re, B_im, C_re, C_im,
                               wLbar, wBbr, wBbi, wCtr, wCti);
  for (int l = 0; l < 2; ++l) {
    const float* xin = (l == 0) ? z_input : wx;
    k_ln_bu<<<512, 256, 0, stream>>>(xin, ln1_w, ln1_b, wBbr, wBbi, wfx, wbu, l);
    k_scan<<<16, 256, 0, stream>>>(wbu, wLbar, l);
    k_yproj<<<512, 256, 0, stream>>>(wbu, wCtr, wCti, wfx, Dp, wx, l);
    k_ff<<<512, 256, 0, stream>>>(wx, ln2_w, ln2_b, ff_enc, ff_dec, l);
  }
  k_toa1<<<512, 256, 0, stream>>>(wx, toA_w1, toA_b1, wh1);
  k_gemm<<<dim3(32, 128), 256, 0, stream>>>(wh1, toA_w2, toA_b2, mask_A, dt, wX);
  k_neumann<<<16384, 256, 0, stream>>>(wX);
  k_traj<<<32, 512, 0, stream>>>(z_input, wX, (float*)d_out);
}

// Round 3
// 555.436 us; speedup vs baseline: 1.7419x; 1.7419x over previous
//
#include <hip/hip_runtime.h>

#define DI __device__ __forceinline__

typedef unsigned short u16;
typedef unsigned int u32;
typedef __attribute__((ext_vector_type(8))) short shortx8;
typedef __attribute__((ext_vector_type(4))) float floatx4;

DI float u2f(u32 x) { union { u32 u; float f; } v; v.u = x; return v.f; }
DI u32 f2u(float x) { union { u32 u; float f; } v; v.f = x; return v.u; }
DI float bflo(u32 w) { return u2f(w << 16); }
DI float bfhi(u32 w) { return u2f(w & 0xffff0000u); }
DI u16 f2bf(float f) {  // RNE
  u32 u = f2u(f);
  u32 r = (u + 0x7fffu + ((u >> 16) & 1u)) >> 16;
  return (u16)r;
}

DI float wsum64(float v) {
  v += __shfl_xor(v, 32);
  v += __shfl_xor(v, 16);
  v += __shfl_xor(v, 8);
  v += __shfl_xor(v, 4);
  v += __shfl_xor(v, 2);
  v += __shfl_xor(v, 1);
  return v;
}

DI float gelu_ex(float y) { return 0.5f * y * (1.0f + erff(y * 0.7071067811865476f)); }
DI float softplus_ex(float x) { return x > 0.f ? x + log1pf(expf(-x)) : log1pf(expf(x)); }

// ---------------- precompute: Lbar, Bbar ([h][p] planes), C transposed ([p][h] planes)
__global__ void k_pre(const float* __restrict__ Lam_re, const float* __restrict__ Lam_im,
                      const float* __restrict__ log_step,
                      const float* __restrict__ B_re, const float* __restrict__ B_im,
                      const float* __restrict__ C_re, const float* __restrict__ C_im,
                      float* __restrict__ wLbar, float* __restrict__ wBbr, float* __restrict__ wBbi,
                      float* __restrict__ wCtr, float* __restrict__ wCti) {
  int l = blockIdx.x;
  int p = threadIdx.x;  // 128
  int idx = l * 128 + p;
  float step = expf(log_step[idx]);
  float lre = -expf(Lam_re[idx]);
  float lim = Lam_im[idx];
  float er = expf(lre * step);
  float Lr = er * cosf(lim * step);
  float Li = er * sinf(lim * step);
  wLbar[idx * 2] = Lr;
  wLbar[idx * 2 + 1] = Li;
  float inv = 1.0f / (lre * lre + lim * lim);
  float nr = Lr - 1.0f, ni = Li;
  float qr = (nr * lre + ni * lim) * inv;
  float qi = (ni * lre - nr * lim) * inv;
  for (int h = 0; h < 64; ++h) {
    float br = B_re[idx * 64 + h], bim = B_im[idx * 64 + h];
    wBbr[(l * 64 + h) * 128 + p] = qr * br - qi * bim;
    wBbi[(l * 64 + h) * 128 + p] = qr * bim + qi * br;
    wCtr[idx * 64 + h] = C_re[(l * 64 + h) * 128 + p];
    wCti[idx * 64 + h] = C_im[(l * 64 + h) * 128 + p];
  }
}

// ---------------- transpose toA_w2 (128x4096 f32) -> w2T bf16 [4096][128]
__global__ __launch_bounds__(256) void k_prew(const float* __restrict__ w2, u16* __restrict__ w2T) {
  __shared__ float s[128][65];
  int t = threadIdx.x;
  int n0 = blockIdx.x * 64;
  for (int i = 0; i < 32; ++i) {
    int e = i * 256 + t;  // 0..8191
    int k = e >> 6, n = e & 63;
    s[k][n] = w2[(size_t)k * 4096 + n0 + n];
  }
  __syncthreads();
  for (int i = 0; i < 16; ++i) {
    int e = i * 256 + t;
    int n = e >> 6, kp = e & 63;
    u32 pk = (u32)f2bf(s[kp * 2][n]) | ((u32)f2bf(s[kp * 2 + 1][n]) << 16);
    ((u32*)w2T)[(size_t)(n0 + n) * 64 + kp] = pk;
  }
}

// ---------------- LN1 + Bu = einsum('ph,blh->blp')
__global__ __launch_bounds__(256) void k_ln_bu(
    const float* __restrict__ xin, const float* __restrict__ lnw, const float* __restrict__ lnb,
    const float* __restrict__ wBbr, const float* __restrict__ wBbi,
    float* __restrict__ fxg, float2* __restrict__ bu, int layer) {
  __shared__ float sbr[64 * 128];
  __shared__ float sbi[64 * 128];
  int t = threadIdx.x, w = t >> 6, lane = t & 63;
  {
    const float* br = wBbr + (size_t)layer * 8192;
    const float* bi = wBbi + (size_t)layer * 8192;
    for (int e = t; e < 8192; e += 256) { sbr[e] = br[e]; sbi[e] = bi[e]; }
  }
  float wv = lnw[layer * 64 + lane], bv = lnb[layer * 64 + lane];
  __syncthreads();
  int row0 = blockIdx.x * 32 + w * 8;
  float fxv[8];
#pragma unroll
  for (int rr = 0; rr < 8; ++rr) {
    size_t r = row0 + rr;
    float x = xin[r * 64 + lane];
    float mu = wsum64(x) * 0.015625f;
    float d = x - mu;
    float var = wsum64(d * d) * 0.015625f;
    float fx = d * rsqrtf(var + 1e-5f) * wv + bv;
    fxv[rr] = fx;
    fxg[r * 64 + lane] = fx;
  }
  float ar0[8] = {}, ai0[8] = {}, ar1[8] = {}, ai1[8] = {};
  for (int h = 0; h < 64; ++h) {
    float b0r = sbr[h * 128 + lane], b0i = sbi[h * 128 + lane];
    float b1r = sbr[h * 128 + lane + 64], b1i = sbi[h * 128 + lane + 64];
#pragma unroll
    for (int rr = 0; rr < 8; ++rr) {
      float f = __shfl(fxv[rr], h);
      ar0[rr] = fmaf(b0r, f, ar0[rr]);
      ai0[rr] = fmaf(b0i, f, ai0[rr]);
      ar1[rr] = fmaf(b1r, f, ar1[rr]);
      ai1[rr] = fmaf(b1i, f, ai1[rr]);
    }
  }
#pragma unroll
  for (int rr = 0; rr < 8; ++rr) {
    size_t r = row0 + rr;
    bu[r * 128 + lane] = make_float2(ar0[rr], ai0[rr]);
    bu[r * 128 + lane + 64] = make_float2(ar1[rr], ai1[rr]);
  }
}

// ---------------- diagonal complex inclusive scan over L (in place)
__global__ __launch_bounds__(256) void k_scan(float2* __restrict__ bu,
                                              const float* __restrict__ wLbar, int layer) {
  int gid = blockIdx.x * 256 + threadIdx.x;
  int b = gid >> 7, p = gid & 127;
  float Lr = wLbar[(layer * 128 + p) * 2];
  float Li = wLbar[(layer * 128 + p) * 2 + 1];
  float2* ptr = bu + ((size_t)b * 512 * 128 + p);
  float xr = 0.f, xi = 0.f;
#pragma unroll 8
  for (int l = 0; l < 512; ++l) {
    float2 v = ptr[(size_t)l * 128];
    float nr = fmaf(Lr, xr, fmaf(-Li, xi, v.x));
    float ni = fmaf(Lr, xi, fmaf(Li, xr, v.y));
    xr = nr;
    xi = ni;
    ptr[(size_t)l * 128] = make_float2(xr, xi);
  }
}

// ---------------- y = 2*Re(C xs) + D*u ; x = gelu(y) + fx
__global__ __launch_bounds__(256) void k_yproj(
    const float2* __restrict__ xs, const float* __restrict__ wCtr, const float* __restrict__ wCti,
    const float* __restrict__ fxg, const float* __restrict__ Dp,
    float* __restrict__ xout, int layer) {
  __shared__ float ctr[64 * 64];
  __shared__ float cti[64 * 64];
  __shared__ float2 xsh[4][8][64];
  int t = threadIdx.x, w = t >> 6, lane = t & 63;
  int row0 = blockIdx.x * 32 + w * 8;
  float acc[8] = {};
  for (int ph = 0; ph < 2; ++ph) {
    __syncthreads();
    {
      const float* sr = wCtr + ((size_t)layer * 128 + ph * 64) * 64;
      const float* si = wCti + ((size_t)layer * 128 + ph * 64) * 64;
      for (int e = t; e < 4096; e += 256) { ctr[e] = sr[e]; cti[e] = si[e]; }
    }
#pragma unroll
    for (int rr = 0; rr < 8; ++rr) {
      size_t r = row0 + rr;
      xsh[w][rr][lane] = xs[r * 128 + ph * 64 + lane];
    }
    __syncthreads();
    for (int p = 0; p < 64; ++p) {
      float cr = ctr[p * 64 + lane];
      float ci = cti[p * 64 + lane];
#pragma unroll
      for (int rr = 0; rr < 8; ++rr) {
        float2 xv = xsh[w][rr][p];
        acc[rr] = fmaf(cr, xv.x, fmaf(-ci, xv.y, acc[rr]));
      }
    }
  }
  float Dv = Dp[layer * 64 + lane];
#pragma unroll
  for (int rr = 0; rr < 8; ++rr) {
    size_t r = row0 + rr;
    float u = fxg[r * 64 + lane];
    float y = 2.f * acc[rr] + Dv * u;
    xout[r * 64 + lane] = gelu_ex(y) + u;
  }
}

// ---------------- LN2 + GLU FFN + residual (in place on x)
__global__ __launch_bounds__(256) void k_ff(
    float* __restrict__ xio, const float* __restrict__ lnw, const float* __restrict__ lnb,
    const float* __restrict__ encw, const float* __restrict__ decw, int layer) {
  __shared__ float enc[64 * 128];
  __shared__ float dec[64 * 64];
  int t = threadIdx.x, w = t >> 6, lane = t & 63;
  {
    const float* e = encw + (size_t)layer * 8192;
    for (int i = t; i < 8192; i += 256) enc[i] = e[i];
    const float* d = decw + (size_t)layer * 4096;
    for (int i = t; i < 4096; i += 256) dec[i] = d[i];
  }
  float wv = lnw[layer * 64 + lane], bv = lnb[layer * 64 + lane];
  __syncthreads();
  int row0 = blockIdx.x * 32 + w * 8;
  float fx2v[8];
#pragma unroll
  for (int rr = 0; rr < 8; ++rr) {
    size_t r = row0 + rr;
    float x = xio[r * 64 + lane];
    float mu = wsum64(x) * 0.015625f;
    float d = x - mu;
    float var = wsum64(d * d) * 0.015625f;
    fx2v[rr] = d * rsqrtf(var + 1e-5f) * wv + bv;
  }
  float h0[8] = {}, h1v[8] = {};
  for (int h = 0; h < 64; ++h) {
    float e0 = enc[h * 128 + lane], e1 = enc[h * 128 + lane + 64];
#pragma unroll
    for (int rr = 0; rr < 8; ++rr) {
      float f = __shfl(fx2v[rr], h);
      h0[rr] = fmaf(e0, f, h0[rr]);
      h1v[rr] = fmaf(e1, f, h1v[rr]);
    }
  }
  float gv[8];
#pragma unroll
  for (int rr = 0; rr < 8; ++rr) gv[rr] = h0[rr] * gelu_ex(h1v[rr]);
  float o[8] = {};
  for (int j = 0; j < 64; ++j) {
    float dv = dec[j * 64 + lane];
#pragma unroll
    for (int rr = 0; rr < 8; ++rr) {
      float gj = __shfl(gv[rr], j);
      o[rr] = fmaf(dv, gj, o[rr]);
    }
  }
#pragma unroll
  for (int rr = 0; rr < 8; ++rr) {
    size_t r = row0 + rr;
    xio[r * 64 + lane] = o[rr] + fx2v[rr];
  }
}

// ---------------- h1 = softplus(x @ toA_w1 + b1) -> bf16 [16384][128]
__global__ __launch_bounds__(256) void k_toa1(
    const float* __restrict__ xin, const float* __restrict__ w1, const float* __restrict__ b1,
    u16* __restrict__ h1out) {
  __shared__ float w1s[64 * 128];
  int t = threadIdx.x, w = t >> 6, lane = t & 63;
  for (int i = t; i < 8192; i += 256) w1s[i] = w1[i];
  float bb0 = b1[lane], bb1 = b1[lane + 64];
  __syncthreads();
  int row0 = blockIdx.x * 32 + w * 8;
  float xv[8];
#pragma unroll
  for (int rr = 0; rr < 8; ++rr) xv[rr] = xin[(size_t)(row0 + rr) * 64 + lane];
  float a0[8] = {}, a1[8] = {};
  for (int h = 0; h < 64; ++h) {
    float e0 = w1s[h * 128 + lane], e1 = w1s[h * 128 + lane + 64];
#pragma unroll
    for (int rr = 0; rr < 8; ++rr) {
      float f = __shfl(xv[rr], h);
      a0[rr] = fmaf(e0, f, a0[rr]);
      a1[rr] = fmaf(e1, f, a1[rr]);
    }
  }
#pragma unroll
  for (int rr = 0; rr < 8; ++rr) {
    size_t r = row0 + rr;
    float v0 = softplus_ex(a0[rr] + bb0);  // k = lane
    float v1 = softplus_ex(a1[rr] + bb1);  // k = lane + 64
    // pack k-pairs: u32 slot l of the row holds k = 2l, 2l+1
    int sl = (2 * lane) & 63;
    float ea = __shfl(v0, sl), eb = __shfl(v1, sl);
    float oa = __shfl(v0, sl + 1), ob = __shfl(v1, sl + 1);
    float lo = (lane < 32) ? ea : eb;
    float hi = (lane < 32) ? oa : ob;
    ((u32*)h1out)[r * 64 + lane] = (u32)f2bf(lo) | ((u32)f2bf(hi) << 16);
  }
}

// ---------------- MFMA big GEMM: computes X^T = w2T . h1^T, epilogue applies dt/b2/mask
// X[m][n] = 0.5*dt[m]*(sum_k h1[m][k] w2[k][n] + b2[n])*mask[n], stored bf16 row-major.
__global__ __launch_bounds__(256) void k_gemm_mfma(
    const u16* __restrict__ w2T,  // [4096][128] bf16
    const u16* __restrict__ h1,   // [16384][128] bf16
    const float* __restrict__ b2, const float* __restrict__ mask,
    const float* __restrict__ dt, u16* __restrict__ Xout) {
  __shared__ __align__(16) u16 As[128 * 128];  // w2T panel (rows n, k contiguous), swizzled
  __shared__ __align__(16) u16 Bs[128 * 128];  // h1 panel  (rows m, k contiguous), swizzled
  int t = threadIdx.x;
  int bn = blockIdx.x;  // 0..31
  int bm = blockIdx.y;  // 0..127
  {
    const u16* srcA = w2T + (size_t)(bn * 128) * 128;
    const u16* srcB = h1 + (size_t)(bm * 128) * 128;
#pragma unroll
    for (int i = 0; i < 8; ++i) {
      int r = i * 16 + (t >> 4);
      int gs = t & 15;
      int gsw = (gs & 8) | ((gs ^ r) & 7);
      uint4 va = *(const uint4*)(srcA + r * 128 + gs * 8);
      *(uint4*)(As + r * 128 + gsw * 8) = va;
      uint4 vb = *(const uint4*)(srcB + r * 128 + gs * 8);
      *(uint4*)(Bs + r * 128 + gsw * 8) = vb;
    }
  }
  __syncthreads();
  int w = t >> 6, l = t & 63;
  int n0 = (w & 1) * 64, m0 = (w >> 1) * 64;
  int lr = l & 15, kg = l >> 4;
  floatx4 acc[4][4];
#pragma unroll
  for (int i = 0; i < 4; ++i)
#pragma unroll
    for (int j = 0; j < 4; ++j) acc[i][j] = (floatx4){0.f, 0.f, 0.f, 0.f};
#pragma unroll
  for (int kk = 0; kk < 4; ++kk) {
    int g = kk * 4 + kg;  // 0..15
    shortx8 af[4], bf[4];
#pragma unroll
    for (int ni = 0; ni < 4; ++ni) {
      int r = n0 + ni * 16 + lr;
      int gsw = (g & 8) | ((g ^ r) & 7);
      af[ni] = *(const shortx8*)(As + r * 128 + gsw * 8);
    }
#pragma unroll
    for (int mi = 0; mi < 4; ++mi) {
      int r = m0 + mi * 16 + lr;
      int gsw = (g & 8) | ((g ^ r) & 7);
      bf[mi] = *(const shortx8*)(Bs + r * 128 + gsw * 8);
    }
#pragma unroll
    for (int ni = 0; ni < 4; ++ni)
#pragma unroll
      for (int mi = 0; mi < 4; ++mi)
        acc[ni][mi] = __builtin_amdgcn_mfma_f32_16x16x32_bf16(af[ni], bf[mi], acc[ni][mi], 0, 0, 0);
  }
  // lane holds X[m][q0..q0+3] for each tile: m = bm*128+m0+mi*16+(l&15), q0=(l>>4)*4
  int q = (l >> 4) * 4;
#pragma unroll
  for (int mi = 0; mi < 4; ++mi) {
    int m = bm * 128 + m0 + mi * 16 + lr;
    float dv = 0.5f * dt[m];
#pragma unroll
    for (int ni = 0; ni < 4; ++ni) {
      int nl = n0 + ni * 16 + q;
      int n = bn * 128 + nl;
      float4 bb = *(const float4*)&b2[n];
      float4 mk = *(const float4*)&mask[n];
      floatx4 a = acc[ni][mi];
      float x0 = dv * (a[0] + bb.x) * mk.x;
      float x1 = dv * (a[1] + bb.y) * mk.y;
      float x2 = dv * (a[2] + bb.z) * mk.z;
      float x3 = dv * (a[3] + bb.w) * mk.w;
      u32 lo = (u32)f2bf(x0) | ((u32)f2bf(x1) << 16);
      u32 hi = (u32)f2bf(x2) | ((u32)f2bf(x3) << 16);
      *(uint2*)&Xout[(size_t)m * 4096 + n] = make_uint2(lo, hi);
    }
  }
}

// ---------------- MFMA Neumann: E = 2(X + X^2 + X^3) in place, 2 systems/block
__global__ __launch_bounds__(256) void k_neumann2(u16* __restrict__ Xg) {
  __shared__ __align__(16) u16 Xrm[2][64 * 64];   // X row-major, swizzled
  __shared__ __align__(16) u16 XTrm[2][64 * 64];  // X^T row-major, swizzled
  __shared__ __align__(16) u16 X2rm[2][64 * 64];  // X^2 row-major, swizzled
  int t = threadIdx.x, w = t >> 6, l = t & 63;
  int sys = w >> 1, half = w & 1;
  u16* Xp = Xg + ((size_t)blockIdx.x * 2 + sys) * 4096;
  int lt = (half << 6) | l;  // 0..127 within system
  // stage X row-major (swizzled granules)
#pragma unroll
  for (int i = 0; i < 4; ++i) {
    int r = i * 16 + (lt >> 3);
    int gs = lt & 7;
    int gsw = (gs ^ r) & 7;
    uint4 v = *(const uint4*)(Xp + r * 64 + gs * 8);
    *(uint4*)(&Xrm[sys][r * 64 + gsw * 8]) = v;
  }
  __syncthreads();
  // transpose into XTrm
  for (int it = 0; it < 32; ++it) {
    int e = it * 128 + lt;  // 0..4095
    int c = e >> 6, r = e & 63;
    int gr = ((c >> 3) ^ r) & 7;
    u16 v = Xrm[sys][r * 64 + gr * 8 + (c & 7)];
    int gw = ((r >> 3) ^ c) & 7;
    XTrm[sys][c * 64 + gw * 8 + (r & 7)] = v;
  }
  __syncthreads();
  int lr = l & 15, kg = l >> 4;
  // matmul1: (X^2)^T = X^T . X^T  (A from XTrm rows, B from Xrm rows)
  floatx4 acc[2][4];
#pragma unroll
  for (int i = 0; i < 2; ++i)
#pragma unroll
    for (int j = 0; j < 4; ++j) acc[i][j] = (floatx4){0.f, 0.f, 0.f, 0.f};
#pragma unroll
  for (int kk = 0; kk < 2; ++kk) {
    int g = kk * 4 + kg;  // 0..7
    shortx8 af[2], bf[4];
#pragma unroll
    for (int i = 0; i < 2; ++i) {
      int r = (half * 2 + i) * 16 + lr;
      af[i] = *(const shortx8*)(&XTrm[sys][r * 64 + ((g ^ r) & 7) * 8]);
    }
#pragma unroll
    for (int j = 0; j < 4; ++j) {
      int r = j * 16 + lr;
      bf[j] = *(const shortx8*)(&Xrm[sys][r * 64 + ((g ^ r) & 7) * 8]);
    }
#pragma unroll
    for (int i = 0; i < 2; ++i)
#pragma unroll
      for (int j = 0; j < 4; ++j)
        acc[i][j] = __builtin_amdgcn_mfma_f32_16x16x32_bf16(af[i], bf[j], acc[i][j], 0, 0, 0);
  }
  // write X^2 row-major: lane holds X2[p][q0..q0+3], p = j*16+lr, q0 = (half*2+i)*16+(l>>4)*4
#pragma unroll
  for (int i = 0; i < 2; ++i)
#pragma unroll
    for (int j = 0; j < 4; ++j) {
      int p = j * 16 + lr;
      int q0 = (half * 2 + i) * 16 + (l >> 4) * 4;
      floatx4 a = acc[i][j];
      u32 lo = (u32)f2bf(a[0]) | ((u32)f2bf(a[1]) << 16);
      u32 hi = (u32)f2bf(a[2]) | ((u32)f2bf(a[3]) << 16);
      int gw = ((q0 >> 3) ^ p) & 7;
      *(uint2*)(&X2rm[sys][p * 64 + gw * 8 + (q0 & 7)]) = make_uint2(lo, hi);
    }
  __syncthreads();
  // matmul2: (X^3)^T = X^T . (X^2)^T  (A from XTrm rows, B from X2rm rows)
#pragma unroll
  for (int i = 0; i < 2; ++i)
#pragma unroll
    for (int j = 0; j < 4; ++j) acc[i][j] = (floatx4){0.f, 0.f, 0.f, 0.f};
#pragma unroll
  for (int kk = 0; kk < 2; ++kk) {
    int g = kk * 4 + kg;
    shortx8 af[2], bf[4];
#pragma unroll
    for (int i = 0; i < 2; ++i) {
      int r = (half * 2 + i) * 16 + lr;
      af[i] = *(const shortx8*)(&XTrm[sys][r * 64 + ((g ^ r) & 7) * 8]);
    }
#pragma unroll
    for (int j = 0; j < 4; ++j) {
      int r = j * 16 + lr;
      bf[j] = *(const shortx8*)(&X2rm[sys][r * 64 + ((g ^ r) & 7) * 8]);
    }
#pragma unroll
    for (int i = 0; i < 2; ++i)
#pragma unroll
      for (int j = 0; j < 4; ++j)
        acc[i][j] = __builtin_amdgcn_mfma_f32_16x16x32_bf16(af[i], bf[j], acc[i][j], 0, 0, 0);
  }
  // E = 2(X + X2 + X3): lane holds tiles at (p, q0..q0+3)
#pragma unroll
  for (int i = 0; i < 2; ++i)
#pragma unroll
    for (int j = 0; j < 4; ++j) {
      int p = j * 16 + lr;
      int q0 = (half * 2 + i) * 16 + (l >> 4) * 4;
      int g = (q0 >> 3);
      uint2 xv = *(const uint2*)(&Xrm[sys][p * 64 + ((g ^ p) & 7) * 8 + (q0 & 7)]);
      uint2 x2v = *(const uint2*)(&X2rm[sys][p * 64 + ((g ^ p) & 7) * 8 + (q0 & 7)]);
      floatx4 a = acc[i][j];
      float e0 = 2.f * (bflo(xv.x) + bflo(x2v.x) + a[0]);
      float e1 = 2.f * (bfhi(xv.x) + bfhi(x2v.x) + a[1]);
      float e2 = 2.f * (bflo(xv.y) + bflo(x2v.y) + a[2]);
      float e3 = 2.f * (bfhi(xv.y) + bfhi(x2v.y) + a[3]);
      u32 lo = (u32)f2bf(e0) | ((u32)f2bf(e1) << 16);
      u32 hi = (u32)f2bf(e2) | ((u32)f2bf(e3) << 16);
      *(uint2*)(Xp + p * 64 + q0) = make_uint2(lo, hi);
    }
}

// ---------------- sequential trajectory: z_t = z_{t-1} + E[t-1] z_{t-1}  (f32 output)
__global__ __launch_bounds__(512) void k_traj(const float* __restrict__ zin,
                                              const u16* __restrict__ E,
                                              float* __restrict__ out) {
  int b = blockIdx.x, t = threadIdx.x;
  int i = t >> 3, g = t & 7;
  __shared__ float zsh[2][64];
  if (t < 64) {
    float z0 = zin[(size_t)b * 512 * 64 + t];
    zsh[0][t] = z0;
    out[(size_t)b * 512 * 64 + t] = z0;
  }
  __syncthreads();
  const u16* Eb = E + (size_t)b * 512 * 4096 + i * 64 + g * 8;
  uint4 pf0 = *(const uint4*)(Eb + 0 * 4096);
  uint4 pf1 = *(const uint4*)(Eb + 1 * 4096);
  uint4 pf2 = *(const uint4*)(Eb + 2 * 4096);
  uint4 pf3 = *(const uint4*)(Eb + 3 * 4096);
  int cur = 0;
  for (int s0 = 1; s0 <= 509; s0 += 4) {
#pragma unroll
    for (int k = 0; k < 4; ++k) {
      int s = s0 + k;
      if (s > 511) break;
      uint4 mine = (k == 0) ? pf0 : (k == 1) ? pf1 : (k == 2) ? pf2 : pf3;
      if (s + 4 <= 511) {
        uint4 nv = *(const uint4*)(Eb + (size_t)(s + 3) * 4096);
        if (k == 0) pf0 = nv;
        else if (k == 1) pf1 = nv;
        else if (k == 2) pf2 = nv;
        else pf3 = nv;
      }
      const float* zb = &zsh[cur][g * 8];
      float a = bflo(mine.x) * zb[0];
      a = fmaf(bfhi(mine.x), zb[1], a);
      a = fmaf(bflo(mine.y), zb[2], a);
      a = fmaf(bfhi(mine.y), zb[3], a);
      a = fmaf(bflo(mine.z), zb[4], a);
      a = fmaf(bfhi(mine.z), zb[5], a);
      a = fmaf(bflo(mine.w), zb[6], a);
      a = fmaf(bfhi(mine.w), zb[7], a);
      a += __shfl_xor(a, 1);
      a += __shfl_xor(a, 2);
      a += __shfl_xor(a, 4);
      if (g == 0) {
        float zi = a + zsh[cur][i];
        zsh[cur ^ 1][i] = zi;
        out[((size_t)b * 512 + s) * 64 + i] = zi;
      }
      __syncthreads();
      cur ^= 1;
    }
  }
}

extern "C" void kernel_launch(void* const* d_in, const int* in_sizes, int n_in,
                              void* d_out, int out_size, void* d_ws, size_t ws_size,
                              hipStream_t stream) {
  const float* z_input  = (const float*)d_in[0];
  const float* dt       = (const float*)d_in[1];
  const float* ln1_w    = (const float*)d_in[2];
  const float* ln1_b    = (const float*)d_in[3];
  const float* Lam_re   = (const float*)d_in[4];
  const float* Lam_im   = (const float*)d_in[5];
  const float* B_re     = (const float*)d_in[6];
  const float* B_im     = (const float*)d_in[7];
  const float* C_re     = (const float*)d_in[8];
  const float* C_im     = (const float*)d_in[9];
  const float* Dp       = (const float*)d_in[10];
  const float* log_step = (const float*)d_in[11];
  const float* ln2_w    = (const float*)d_in[12];
  const float* ln2_b    = (const float*)d_in[13];
  const float* ff_enc   = (const float*)d_in[14];
  const float* ff_dec   = (const float*)d_in[15];
  const float* toA_w1   = (const float*)d_in[16];
  const float* toA_b1   = (const float*)d_in[17];
  const float* toA_w2   = (const float*)d_in[18];
  const float* toA_b2   = (const float*)d_in[19];
  const float* mask_A   = (const float*)d_in[20];

  char* ws = (char*)d_ws;
  float* wLbar = (float*)(ws + 0);
  float* wBbr  = (float*)(ws + 2048);
  float* wBbi  = (float*)(ws + 67584);
  float* wCtr  = (float*)(ws + 133120);
  float* wCti  = (float*)(ws + 198656);
  float* wfx   = (float*)(ws + 264192);
  float* wx    = (float*)(ws + 4458496);
  float2* wbu  = (float2*)(ws + 8652800);
  u16* wh1     = (u16*)(ws + 25430016);   // [16384][128] bf16
  u16* w2T     = (u16*)(ws + 29624320);   // [4096][128] bf16
  u16* wX      = (u16*)(ws + 30672896);   // [16384][4096] bf16
  if (ws_size < 164890624ull) return;

  k_pre<<<2, 128, 0, stream>>>(Lam_re, Lam_im, log_step, B_re, B_im, C_re, C_im,
                               wLbar, wBbr, wBbi, wCtr, wCti);
  k_prew<<<64, 256, 0, stream>>>(toA_w2, w2T);
  for (int l = 0; l < 2; ++l) {
    const float* xin = (l == 0) ? z_input : wx;
    k_ln_bu<<<512, 256, 0, stream>>>(xin, ln1_w, ln1_b, wBbr, wBbi, wfx, wbu, l);
    k_scan<<<16, 256, 0, stream>>>(wbu, wLbar, l);
    k_yproj<<<512, 256, 0, stream>>>(wbu, wCtr, wCti, wfx, Dp, wx, l);
    k_ff<<<512, 256, 0, stream>>>(wx, ln2_w, ln2_b, ff_enc, ff_dec, l);
  }
  k_toa1<<<512, 256, 0, stream>>>(wx, toA_w1, toA_b1, wh1);
  k_gemm_mfma<<<dim3(32, 128), 256, 0, stream>>>(w2T, wh1, toA_b2, mask_A, dt, wX);
  k_neumann2<<<8192, 256, 0, stream>>>(wX);
  k_traj<<<32, 512, 0, stream>>>(z_input, wX, (float*)d_out);
}

// Round 4
// 536.771 us; speedup vs baseline: 1.8024x; 1.0348x over previous
//
#include <hip/hip_runtime.h>

#define DI __device__ __forceinline__

typedef unsigned short u16;
typedef unsigned int u32;
typedef __attribute__((ext_vector_type(8))) short shortx8;
typedef __attribute__((ext_vector_type(4))) float floatx4;

DI float u2f(u32 x) { union { u32 u; float f; } v; v.u = x; return v.f; }
DI u32 f2u(float x) { union { u32 u; float f; } v; v.f = x; return v.u; }
DI float bflo(u32 w) { return u2f(w << 16); }
DI float bfhi(u32 w) { return u2f(w & 0xffff0000u); }
DI float bf1(u16 w) { return u2f(((u32)w) << 16); }
DI u16 f2bf(float f) {  // RNE
  u32 u = f2u(f);
  u32 r = (u + 0x7fffu + ((u >> 16) & 1u)) >> 16;
  return (u16)r;
}

DI float wsum64(float v) {
  v += __shfl_xor(v, 32);
  v += __shfl_xor(v, 16);
  v += __shfl_xor(v, 8);
  v += __shfl_xor(v, 4);
  v += __shfl_xor(v, 2);
  v += __shfl_xor(v, 1);
  return v;
}

DI float gelu_ex(float y) { return 0.5f * y * (1.0f + erff(y * 0.7071067811865476f)); }
DI float softplus_ex(float x) { return x > 0.f ? x + log1pf(expf(-x)) : log1pf(expf(x)); }

// ---------------- precompute: Lbar, Bbar ([h][p] planes), C transposed ([p][h] planes)
__global__ void k_pre(const float* __restrict__ Lam_re, const float* __restrict__ Lam_im,
                      const float* __restrict__ log_step,
                      const float* __restrict__ B_re, const float* __restrict__ B_im,
                      const float* __restrict__ C_re, const float* __restrict__ C_im,
                      float* __restrict__ wLbar, float* __restrict__ wBbr, float* __restrict__ wBbi,
                      float* __restrict__ wCtr, float* __restrict__ wCti) {
  int l = blockIdx.x;
  int p = threadIdx.x;  // 128
  int idx = l * 128 + p;
  float step = expf(log_step[idx]);
  float lre = -expf(Lam_re[idx]);
  float lim = Lam_im[idx];
  float er = expf(lre * step);
  float Lr = er * cosf(lim * step);
  float Li = er * sinf(lim * step);
  wLbar[idx * 2] = Lr;
  wLbar[idx * 2 + 1] = Li;
  float inv = 1.0f / (lre * lre + lim * lim);
  float nr = Lr - 1.0f, ni = Li;
  float qr = (nr * lre + ni * lim) * inv;
  float qi = (ni * lre - nr * lim) * inv;
  for (int h = 0; h < 64; ++h) {
    float br = B_re[idx * 64 + h], bim = B_im[idx * 64 + h];
    wBbr[(l * 64 + h) * 128 + p] = qr * br - qi * bim;
    wBbi[(l * 64 + h) * 128 + p] = qr * bim + qi * br;
    wCtr[idx * 64 + h] = C_re[(l * 64 + h) * 128 + p];
    wCti[idx * 64 + h] = C_im[(l * 64 + h) * 128 + p];
  }
}

// ---------------- transpose toA_w2 (128x4096 f32) -> w2T bf16 [4096][128]
__global__ __launch_bounds__(256) void k_prew(const float* __restrict__ w2, u16* __restrict__ w2T) {
  __shared__ float s[128][65];
  int t = threadIdx.x;
  int n0 = blockIdx.x * 64;
  for (int i = 0; i < 32; ++i) {
    int e = i * 256 + t;  // 0..8191
    int k = e >> 6, n = e & 63;
    s[k][n] = w2[(size_t)k * 4096 + n0 + n];
  }
  __syncthreads();
  for (int i = 0; i < 16; ++i) {
    int e = i * 256 + t;
    int n = e >> 6, kp = e & 63;
    u32 pk = (u32)f2bf(s[kp * 2][n]) | ((u32)f2bf(s[kp * 2 + 1][n]) << 16);
    ((u32*)w2T)[(size_t)(n0 + n) * 64 + kp] = pk;
  }
}

// ---------------- LN1 + Bu = einsum('ph,blh->blp')
__global__ __launch_bounds__(256) void k_ln_bu(
    const float* __restrict__ xin, const float* __restrict__ lnw, const float* __restrict__ lnb,
    const float* __restrict__ wBbr, const float* __restrict__ wBbi,
    float* __restrict__ fxg, float2* __restrict__ bu, int layer) {
  __shared__ float sbr[64 * 128];
  __shared__ float sbi[64 * 128];
  int t = threadIdx.x, w = t >> 6, lane = t & 63;
  {
    const float* br = wBbr + (size_t)layer * 8192;
    const float* bi = wBbi + (size_t)layer * 8192;
    for (int e = t; e < 8192; e += 256) { sbr[e] = br[e]; sbi[e] = bi[e]; }
  }
  float wv = lnw[layer * 64 + lane], bv = lnb[layer * 64 + lane];
  __syncthreads();
  int row0 = blockIdx.x * 32 + w * 8;
  float fxv[8];
#pragma unroll
  for (int rr = 0; rr < 8; ++rr) {
    size_t r = row0 + rr;
    float x = xin[r * 64 + lane];
    float mu = wsum64(x) * 0.015625f;
    float d = x - mu;
    float var = wsum64(d * d) * 0.015625f;
    float fx = d * rsqrtf(var + 1e-5f) * wv + bv;
    fxv[rr] = fx;
    fxg[r * 64 + lane] = fx;
  }
  float ar0[8] = {}, ai0[8] = {}, ar1[8] = {}, ai1[8] = {};
  for (int h = 0; h < 64; ++h) {
    float b0r = sbr[h * 128 + lane], b0i = sbi[h * 128 + lane];
    float b1r = sbr[h * 128 + lane + 64], b1i = sbi[h * 128 + lane + 64];
#pragma unroll
    for (int rr = 0; rr < 8; ++rr) {
      float f = __shfl(fxv[rr], h);
      ar0[rr] = fmaf(b0r, f, ar0[rr]);
      ai0[rr] = fmaf(b0i, f, ai0[rr]);
      ar1[rr] = fmaf(b1r, f, ar1[rr]);
      ai1[rr] = fmaf(b1i, f, ai1[rr]);
    }
  }
#pragma unroll
  for (int rr = 0; rr < 8; ++rr) {
    size_t r = row0 + rr;
    bu[r * 128 + lane] = make_float2(ar0[rr], ai0[rr]);
    bu[r * 128 + lane + 64] = make_float2(ar1[rr], ai1[rr]);
  }
}

// ---------------- diagonal complex inclusive scan over L (in place)
__global__ __launch_bounds__(256) void k_scan(float2* __restrict__ bu,
                                              const float* __restrict__ wLbar, int layer) {
  int gid = blockIdx.x * 256 + threadIdx.x;
  int b = gid >> 7, p = gid & 127;
  float Lr = wLbar[(layer * 128 + p) * 2];
  float Li = wLbar[(layer * 128 + p) * 2 + 1];
  float2* ptr = bu + ((size_t)b * 512 * 128 + p);
  float xr = 0.f, xi = 0.f;
#pragma unroll 8
  for (int l = 0; l < 512; ++l) {
    float2 v = ptr[(size_t)l * 128];
    float nr = fmaf(Lr, xr, fmaf(-Li, xi, v.x));
    float ni = fmaf(Lr, xi, fmaf(Li, xr, v.y));
    xr = nr;
    xi = ni;
    ptr[(size_t)l * 128] = make_float2(xr, xi);
  }
}

// ---------------- y = 2*Re(C xs) + D*u ; x = gelu(y) + fx
__global__ __launch_bounds__(256) void k_yproj(
    const float2* __restrict__ xs, const float* __restrict__ wCtr, const float* __restrict__ wCti,
    const float* __restrict__ fxg, const float* __restrict__ Dp,
    float* __restrict__ xout, int layer) {
  __shared__ float ctr[64 * 64];
  __shared__ float cti[64 * 64];
  __shared__ float2 xsh[4][8][64];
  int t = threadIdx.x, w = t >> 6, lane = t & 63;
  int row0 = blockIdx.x * 32 + w * 8;
  float acc[8] = {};
  for (int ph = 0; ph < 2; ++ph) {
    __syncthreads();
    {
      const float* sr = wCtr + ((size_t)layer * 128 + ph * 64) * 64;
      const float* si = wCti + ((size_t)layer * 128 + ph * 64) * 64;
      for (int e = t; e < 4096; e += 256) { ctr[e] = sr[e]; cti[e] = si[e]; }
    }
#pragma unroll
    for (int rr = 0; rr < 8; ++rr) {
      size_t r = row0 + rr;
      xsh[w][rr][lane] = xs[r * 128 + ph * 64 + lane];
    }
    __syncthreads();
    for (int p = 0; p < 64; ++p) {
      float cr = ctr[p * 64 + lane];
      float ci = cti[p * 64 + lane];
#pragma unroll
      for (int rr = 0; rr < 8; ++rr) {
        float2 xv = xsh[w][rr][p];
        acc[rr] = fmaf(cr, xv.x, fmaf(-ci, xv.y, acc[rr]));
      }
    }
  }
  float Dv = Dp[layer * 64 + lane];
#pragma unroll
  for (int rr = 0; rr < 8; ++rr) {
    size_t r = row0 + rr;
    float u = fxg[r * 64 + lane];
    float y = 2.f * acc[rr] + Dv * u;
    xout[r * 64 + lane] = gelu_ex(y) + u;
  }
}

// ---------------- LN2 + GLU FFN + residual (in place on x)
__global__ __launch_bounds__(256) void k_ff(
    float* __restrict__ xio, const float* __restrict__ lnw, const float* __restrict__ lnb,
    const float* __restrict__ encw, const float* __restrict__ decw, int layer) {
  __shared__ float enc[64 * 128];
  __shared__ float dec[64 * 64];
  int t = threadIdx.x, w = t >> 6, lane = t & 63;
  {
    const float* e = encw + (size_t)layer * 8192;
    for (int i = t; i < 8192; i += 256) enc[i] = e[i];
    const float* d = decw + (size_t)layer * 4096;
    for (int i = t; i < 4096; i += 256) dec[i] = d[i];
  }
  float wv = lnw[layer * 64 + lane], bv = lnb[layer * 64 + lane];
  __syncthreads();
  int row0 = blockIdx.x * 32 + w * 8;
  float fx2v[8];
#pragma unroll
  for (int rr = 0; rr < 8; ++rr) {
    size_t r = row0 + rr;
    float x = xio[r * 64 + lane];
    float mu = wsum64(x) * 0.015625f;
    float d = x - mu;
    float var = wsum64(d * d) * 0.015625f;
    fx2v[rr] = d * rsqrtf(var + 1e-5f) * wv + bv;
  }
  float h0[8] = {}, h1v[8] = {};
  for (int h = 0; h < 64; ++h) {
    float e0 = enc[h * 128 + lane], e1 = enc[h * 128 + lane + 64];
#pragma unroll
    for (int rr = 0; rr < 8; ++rr) {
      float f = __shfl(fx2v[rr], h);
      h0[rr] = fmaf(e0, f, h0[rr]);
      h1v[rr] = fmaf(e1, f, h1v[rr]);
    }
  }
  float gv[8];
#pragma unroll
  for (int rr = 0; rr < 8; ++rr) gv[rr] = h0[rr] * gelu_ex(h1v[rr]);
  float o[8] = {};
  for (int j = 0; j < 64; ++j) {
    float dv = dec[j * 64 + lane];
#pragma unroll
    for (int rr = 0; rr < 8; ++rr) {
      float gj = __shfl(gv[rr], j);
      o[rr] = fmaf(dv, gj, o[rr]);
    }
  }
#pragma unroll
  for (int rr = 0; rr < 8; ++rr) {
    size_t r = row0 + rr;
    xio[r * 64 + lane] = o[rr] + fx2v[rr];
  }
}

// ---------------- h1 = softplus(x @ toA_w1 + b1) -> bf16 [16384][128]
__global__ __launch_bounds__(256) void k_toa1(
    const float* __restrict__ xin, const float* __restrict__ w1, const float* __restrict__ b1,
    u16* __restrict__ h1out) {
  __shared__ float w1s[64 * 128];
  int t = threadIdx.x, w = t >> 6, lane = t & 63;
  for (int i = t; i < 8192; i += 256) w1s[i] = w1[i];
  float bb0 = b1[lane], bb1 = b1[lane + 64];
  __syncthreads();
  int row0 = blockIdx.x * 32 + w * 8;
  float xv[8];
#pragma unroll
  for (int rr = 0; rr < 8; ++rr) xv[rr] = xin[(size_t)(row0 + rr) * 64 + lane];
  float a0[8] = {}, a1[8] = {};
  for (int h = 0; h < 64; ++h) {
    float e0 = w1s[h * 128 + lane], e1 = w1s[h * 128 + lane + 64];
#pragma unroll
    for (int rr = 0; rr < 8; ++rr) {
      float f = __shfl(xv[rr], h);
      a0[rr] = fmaf(e0, f, a0[rr]);
      a1[rr] = fmaf(e1, f, a1[rr]);
    }
  }
#pragma unroll
  for (int rr = 0; rr < 8; ++rr) {
    size_t r = row0 + rr;
    float v0 = softplus_ex(a0[rr] + bb0);  // k = lane
    float v1 = softplus_ex(a1[rr] + bb1);  // k = lane + 64
    int sl = (2 * lane) & 63;
    float ea = __shfl(v0, sl), eb = __shfl(v1, sl);
    float oa = __shfl(v0, sl + 1), ob = __shfl(v1, sl + 1);
    float lo = (lane < 32) ? ea : eb;
    float hi = (lane < 32) ? oa : ob;
    ((u32*)h1out)[r * 64 + lane] = (u32)f2bf(lo) | ((u32)f2bf(hi) << 16);
  }
}

// ---------------- MFMA big GEMM: X[m][n] = 0.5*dt[m]*(h1@w2 + b2)[m][n]*mask[n] -> bf16
__global__ __launch_bounds__(256) void k_gemm_mfma(
    const u16* __restrict__ w2T,  // [4096][128] bf16
    const u16* __restrict__ h1,   // [16384][128] bf16
    const float* __restrict__ b2, const float* __restrict__ mask,
    const float* __restrict__ dt, u16* __restrict__ Xout) {
  __shared__ __align__(16) u16 As[128 * 128];
  __shared__ __align__(16) u16 Bs[128 * 128];
  int t = threadIdx.x;
  int bn = blockIdx.x;  // 0..31
  int bm = blockIdx.y;  // 0..127
  {
    const u16* srcA = w2T + (size_t)(bn * 128) * 128;
    const u16* srcB = h1 + (size_t)(bm * 128) * 128;
#pragma unroll
    for (int i = 0; i < 8; ++i) {
      int r = i * 16 + (t >> 4);
      int gs = t & 15;
      int gsw = (gs & 8) | ((gs ^ r) & 7);
      uint4 va = *(const uint4*)(srcA + r * 128 + gs * 8);
      *(uint4*)(As + r * 128 + gsw * 8) = va;
      uint4 vb = *(const uint4*)(srcB + r * 128 + gs * 8);
      *(uint4*)(Bs + r * 128 + gsw * 8) = vb;
    }
  }
  __syncthreads();
  int w = t >> 6, l = t & 63;
  int n0 = (w & 1) * 64, m0 = (w >> 1) * 64;
  int lr = l & 15, kg = l >> 4;
  floatx4 acc[4][4];
#pragma unroll
  for (int i = 0; i < 4; ++i)
#pragma unroll
    for (int j = 0; j < 4; ++j) acc[i][j] = (floatx4){0.f, 0.f, 0.f, 0.f};
#pragma unroll
  for (int kk = 0; kk < 4; ++kk) {
    int g = kk * 4 + kg;
    shortx8 af[4], bf[4];
#pragma unroll
    for (int ni = 0; ni < 4; ++ni) {
      int r = n0 + ni * 16 + lr;
      int gsw = (g & 8) | ((g ^ r) & 7);
      af[ni] = *(const shortx8*)(As + r * 128 + gsw * 8);
    }
#pragma unroll
    for (int mi = 0; mi < 4; ++mi) {
      int r = m0 + mi * 16 + lr;
      int gsw = (g & 8) | ((g ^ r) & 7);
      bf[mi] = *(const shortx8*)(Bs + r * 128 + gsw * 8);
    }
#pragma unroll
    for (int ni = 0; ni < 4; ++ni)
#pragma unroll
      for (int mi = 0; mi < 4; ++mi)
        acc[ni][mi] = __builtin_amdgcn_mfma_f32_16x16x32_bf16(af[ni], bf[mi], acc[ni][mi], 0, 0, 0);
  }
  int q = (l >> 4) * 4;
#pragma unroll
  for (int mi = 0; mi < 4; ++mi) {
    int m = bm * 128 + m0 + mi * 16 + lr;
    float dv = 0.5f * dt[m];
#pragma unroll
    for (int ni = 0; ni < 4; ++ni) {
      int nl = n0 + ni * 16 + q;
      int n = bn * 128 + nl;
      float4 bb = *(const float4*)&b2[n];
      float4 mk = *(const float4*)&mask[n];
      floatx4 a = acc[ni][mi];
      float x0 = dv * (a[0] + bb.x) * mk.x;
      float x1 = dv * (a[1] + bb.y) * mk.y;
      float x2 = dv * (a[2] + bb.z) * mk.z;
      float x3 = dv * (a[3] + bb.w) * mk.w;
      u32 lo = (u32)f2bf(x0) | ((u32)f2bf(x1) << 16);
      u32 hi = (u32)f2bf(x2) | ((u32)f2bf(x3) << 16);
      *(uint2*)&Xout[(size_t)m * 4096 + n] = make_uint2(lo, hi);
    }
  }
}

// ---------------- fused chunk kernel: per (b, chunk of 16 t's):
//   A_t = I + 2(X_t + X_t^2 + X_t^3); running product R_j = A_{t0+j}...A_{t0};
//   stores ST_j = (R_j - I)^T bf16 row-major, IN PLACE over X_t.
__global__ __launch_bounds__(256) void k_chunk(u16* __restrict__ Xg) {
  __shared__ __align__(16) u16 Xrm[4096];
  __shared__ __align__(16) u16 XTrm[4096];
  __shared__ __align__(16) u16 X2rm[4096];
  __shared__ __align__(16) u16 Erm[4096];
  __shared__ __align__(16) u16 STb[4096];
  __shared__ float STf[64 * 68];  // fp32 master of S^T, stride 68 (bank-safe)
  int t = threadIdx.x, w = t >> 6, l = t & 63;
  int lr = l & 15, kg = l >> 4;
  int b = blockIdx.x >> 5, c = blockIdx.x & 31;
  u16* base = Xg + ((size_t)(b * 512 + c * 16)) * 4096;
  for (int e = t; e < 64 * 68; e += 256) STf[e] = 0.f;

  for (int j = 0; j < 16; ++j) {
    u16* Xp = base + (size_t)j * 4096;
    __syncthreads();  // STf stable; Xrm free
    // stage X_j (swizzled granules)
    {
      int r = t >> 2, g0 = (t & 3) * 2;
      uint4 v0 = *(const uint4*)(Xp + r * 64 + g0 * 8);
      uint4 v1 = *(const uint4*)(Xp + r * 64 + g0 * 8 + 8);
      *(uint4*)(Xrm + r * 64 + ((g0 ^ r) & 7) * 8) = v0;
      *(uint4*)(Xrm + r * 64 + (((g0 + 1) ^ r) & 7) * 8) = v1;
    }
    // STb = bf16(STf) + I (swizzled)
    {
      int r = t >> 2, q0 = (t & 3) * 16;
      u32 pk[8];
#pragma unroll
      for (int ii = 0; ii < 8; ++ii) {
        float va = STf[r * 68 + q0 + 2 * ii] + ((r == q0 + 2 * ii) ? 1.f : 0.f);
        float vb = STf[r * 68 + q0 + 2 * ii + 1] + ((r == q0 + 2 * ii + 1) ? 1.f : 0.f);
        pk[ii] = (u32)f2bf(va) | ((u32)f2bf(vb) << 16);
      }
      int g0 = (t & 3) * 2;
      *(uint4*)(STb + r * 64 + ((g0 ^ r) & 7) * 8) = make_uint4(pk[0], pk[1], pk[2], pk[3]);
      *(uint4*)(STb + r * 64 + (((g0 + 1) ^ r) & 7) * 8) = make_uint4(pk[4], pk[5], pk[6], pk[7]);
    }
    __syncthreads();
    // transpose Xrm -> XTrm
    for (int it = 0; it < 16; ++it) {
      int e = it * 256 + t;
      int cc = e >> 6, rr = e & 63;
      u16 v = Xrm[rr * 64 + (((cc >> 3) ^ rr) & 7) * 8 + (cc & 7)];
      XTrm[cc * 64 + (((rr >> 3) ^ cc) & 7) * 8 + (rr & 7)] = v;
    }
    __syncthreads();
    // m1: X2 = X*X row-major (af = XTrm rows q, bf = Xrm rows p)
    {
      floatx4 acc[4];
#pragma unroll
      for (int i = 0; i < 4; ++i) acc[i] = (floatx4){0.f, 0.f, 0.f, 0.f};
#pragma unroll
      for (int kk = 0; kk < 2; ++kk) {
        int g = kk * 4 + kg;
        int qrow = w * 16 + lr;
        shortx8 af = *(const shortx8*)(XTrm + qrow * 64 + ((g ^ qrow) & 7) * 8);
#pragma unroll
        for (int j2 = 0; j2 < 4; ++j2) {
          int p = j2 * 16 + lr;
          shortx8 bf = *(const shortx8*)(Xrm + p * 64 + ((g ^ p) & 7) * 8);
          acc[j2] = __builtin_amdgcn_mfma_f32_16x16x32_bf16(af, bf, acc[j2], 0, 0, 0);
        }
      }
#pragma unroll
      for (int j2 = 0; j2 < 4; ++j2) {
        int p = j2 * 16 + lr;
        int q0 = w * 16 + kg * 4;
        floatx4 a = acc[j2];
        u32 lo = (u32)f2bf(a[0]) | ((u32)f2bf(a[1]) << 16);
        u32 hi = (u32)f2bf(a[2]) | ((u32)f2bf(a[3]) << 16);
        *(uint2*)(X2rm + p * 64 + (((q0 >> 3) ^ p) & 7) * 8 + (q0 & 7)) = make_uint2(lo, hi);
      }
    }
    __syncthreads();
    // m2: X3 = X2*X row-major; E = 2(X + X2 + X3) -> Erm
    {
      floatx4 acc[4];
#pragma unroll
      for (int i = 0; i < 4; ++i) acc[i] = (floatx4){0.f, 0.f, 0.f, 0.f};
#pragma unroll
      for (int kk = 0; kk < 2; ++kk) {
        int g = kk * 4 + kg;
        int qrow = w * 16 + lr;
        shortx8 af = *(const shortx8*)(XTrm + qrow * 64 + ((g ^ qrow) & 7) * 8);
#pragma unroll
        for (int j2 = 0; j2 < 4; ++j2) {
          int p = j2 * 16 + lr;
          shortx8 bf = *(const shortx8*)(X2rm + p * 64 + ((g ^ p) & 7) * 8);
          acc[j2] = __builtin_amdgcn_mfma_f32_16x16x32_bf16(af, bf, acc[j2], 0, 0, 0);
        }
      }
#pragma unroll
      for (int j2 = 0; j2 < 4; ++j2) {
        int p = j2 * 16 + lr;
        int q0 = w * 16 + kg * 4;
        int sw = (((q0 >> 3) ^ p) & 7) * 8 + (q0 & 7);
        uint2 xv = *(const uint2*)(Xrm + p * 64 + sw);
        uint2 x2v = *(const uint2*)(X2rm + p * 64 + sw);
        floatx4 a = acc[j2];
        float e0 = 2.f * (bflo(xv.x) + bflo(x2v.x) + a[0]);
        float e1 = 2.f * (bfhi(xv.x) + bfhi(x2v.x) + a[1]);
        float e2 = 2.f * (bflo(xv.y) + bflo(x2v.y) + a[2]);
        float e3 = 2.f * (bfhi(xv.y) + bfhi(x2v.y) + a[3]);
        u32 lo = (u32)f2bf(e0) | ((u32)f2bf(e1) << 16);
        u32 hi = (u32)f2bf(e2) | ((u32)f2bf(e3) << 16);
        *(uint2*)(Erm + p * 64 + sw) = make_uint2(lo, hi);
      }
    }
    __syncthreads();
    // m3: T^T = (I+S^T).E^T row-major (af = Erm rows q, bf = STb rows p); STf += T^T
    {
      floatx4 acc[4];
#pragma unroll
      for (int i = 0; i < 4; ++i) acc[i] = (floatx4){0.f, 0.f, 0.f, 0.f};
#pragma unroll
      for (int kk = 0; kk < 2; ++kk) {
        int g = kk * 4 + kg;
        int qrow = w * 16 + lr;
        shortx8 af = *(const shortx8*)(Erm + qrow * 64 + ((g ^ qrow) & 7) * 8);
#pragma unroll
        for (int j2 = 0; j2 < 4; ++j2) {
          int p = j2 * 16 + lr;
          shortx8 bf = *(const shortx8*)(STb + p * 64 + ((g ^ p) & 7) * 8);
          acc[j2] = __builtin_amdgcn_mfma_f32_16x16x32_bf16(af, bf, acc[j2], 0, 0, 0);
        }
      }
#pragma unroll
      for (int j2 = 0; j2 < 4; ++j2) {
        int p = j2 * 16 + lr;
        int q0 = w * 16 + kg * 4;
        float4 cur = *(float4*)(STf + p * 68 + q0);
        floatx4 a = acc[j2];
        cur.x += a[0]; cur.y += a[1]; cur.z += a[2]; cur.w += a[3];
        *(float4*)(STf + p * 68 + q0) = cur;
      }
    }
    __syncthreads();
    // writeout ST_j bf16 -> global (over X_j), linear layout
    {
      int r = t >> 2, q0 = (t & 3) * 16;
      u32 pk[8];
#pragma unroll
      for (int ii = 0; ii < 8; ++ii) {
        float va = STf[r * 68 + q0 + 2 * ii];
        float vb = STf[r * 68 + q0 + 2 * ii + 1];
        pk[ii] = (u32)f2bf(va) | ((u32)f2bf(vb) << 16);
      }
      *(uint4*)(Xp + r * 64 + q0) = make_uint4(pk[0], pk[1], pk[2], pk[3]);
      *(uint4*)(Xp + r * 64 + q0 + 8) = make_uint4(pk[4], pk[5], pk[6], pk[7]);
    }
  }
}

// ---------------- carry chain: z_{16(c+1)} = (I + S_15^{(c)}) z_{16c}; writes out[t=16c]
__global__ __launch_bounds__(64) void k_carry(const float* __restrict__ zin,
                                              const u16* __restrict__ R,
                                              float* __restrict__ out) {
  int b = blockIdx.x, l = threadIdx.x;
  float cz = zin[(size_t)b * 512 * 64 + l];
  for (int c = 0; c < 32; ++c) {
    out[((size_t)(b * 512 + c * 16)) * 64 + l] = cz;
    const u16* M = R + ((size_t)(b * 512 + c * 16 + 15)) * 4096;
    float a0 = 0.f, a1 = 0.f, a2 = 0.f, a3 = 0.f;
#pragma unroll
    for (int k = 0; k < 64; k += 4) {
      a0 = fmaf(bf1(M[(k + 0) * 64 + l]), __shfl(cz, k + 0), a0);
      a1 = fmaf(bf1(M[(k + 1) * 64 + l]), __shfl(cz, k + 1), a1);
      a2 = fmaf(bf1(M[(k + 2) * 64 + l]), __shfl(cz, k + 2), a2);
      a3 = fmaf(bf1(M[(k + 3) * 64 + l]), __shfl(cz, k + 3), a3);
    }
    cz += (a0 + a1) + (a2 + a3);
  }
}

// ---------------- apply: z_{16c+j+1} = (I + S_j) z_{16c}, j = 0..14
__global__ __launch_bounds__(256) void k_apply(const u16* __restrict__ R,
                                               float* __restrict__ out) {
  __shared__ __align__(16) u16 Ms[4][4096];
  __shared__ float carr[64];
  int t = threadIdx.x, w = t >> 6, l = t & 63;
  int b = blockIdx.x >> 5, c = blockIdx.x & 31;
  const u16* Rb = R + ((size_t)(b * 512 + c * 16)) * 4096;
  if (t < 64) carr[t] = out[((size_t)(b * 512 + c * 16)) * 64 + t];
  for (int j0 = 0; j0 < 16; j0 += 4) {
    __syncthreads();
    {
      int jj = t >> 6, r = t & 63;
      const u16* src = Rb + (size_t)(j0 + jj) * 4096 + (size_t)r * 64;
      u16* dst = Ms[jj] + r * 64;
#pragma unroll
      for (int g = 0; g < 8; ++g) ((uint4*)dst)[g] = ((const uint4*)src)[g];
    }
    __syncthreads();
    int j = j0 + w;
    if (j < 15) {
      const u16* M = Ms[w];
      float a0 = 0.f, a1 = 0.f, a2 = 0.f, a3 = 0.f;
#pragma unroll
      for (int k = 0; k < 64; k += 4) {
        a0 = fmaf(bf1(M[(k + 0) * 64 + l]), carr[k + 0], a0);
        a1 = fmaf(bf1(M[(k + 1) * 64 + l]), carr[k + 1], a1);
        a2 = fmaf(bf1(M[(k + 2) * 64 + l]), carr[k + 2], a2);
        a3 = fmaf(bf1(M[(k + 3) * 64 + l]), carr[k + 3], a3);
      }
      float zo = carr[l] + ((a0 + a1) + (a2 + a3));
      out[((size_t)(b * 512 + c * 16 + j + 1)) * 64 + l] = zo;
    }
  }
}

extern "C" void kernel_launch(void* const* d_in, const int* in_sizes, int n_in,
                              void* d_out, int out_size, void* d_ws, size_t ws_size,
                              hipStream_t stream) {
  const float* z_input  = (const float*)d_in[0];
  const float* dt       = (const float*)d_in[1];
  const float* ln1_w    = (const float*)d_in[2];
  const float* ln1_b    = (const float*)d_in[3];
  const float* Lam_re   = (const float*)d_in[4];
  const float* Lam_im   = (const float*)d_in[5];
  const float* B_re     = (const float*)d_in[6];
  const float* B_im     = (const float*)d_in[7];
  const float* C_re     = (const float*)d_in[8];
  const float* C_im     = (const float*)d_in[9];
  const float* Dp       = (const float*)d_in[10];
  const float* log_step = (const float*)d_in[11];
  const float* ln2_w    = (const float*)d_in[12];
  const float* ln2_b    = (const float*)d_in[13];
  const float* ff_enc   = (const float*)d_in[14];
  const float* ff_dec   = (const float*)d_in[15];
  const float* toA_w1   = (const float*)d_in[16];
  const float* toA_b1   = (const float*)d_in[17];
  const float* toA_w2   = (const float*)d_in[18];
  const float* toA_b2   = (const float*)d_in[19];
  const float* mask_A   = (const float*)d_in[20];

  char* ws = (char*)d_ws;
  float* wLbar = (float*)(ws + 0);
  float* wBbr  = (float*)(ws + 2048);
  float* wBbi  = (float*)(ws + 67584);
  float* wCtr  = (float*)(ws + 133120);
  float* wCti  = (float*)(ws + 198656);
  float* wfx   = (float*)(ws + 264192);
  float* wx    = (float*)(ws + 4458496);
  float2* wbu  = (float2*)(ws + 8652800);
  u16* wh1     = (u16*)(ws + 25430016);   // [16384][128] bf16
  u16* w2T     = (u16*)(ws + 29624320);   // [4096][128] bf16
  u16* wX      = (u16*)(ws + 30672896);   // [16384][4096] bf16 (X, then ST in place)
  if (ws_size < 164890624ull) return;

  k_pre<<<2, 128, 0, stream>>>(Lam_re, Lam_im, log_step, B_re, B_im, C_re, C_im,
                               wLbar, wBbr, wBbi, wCtr, wCti);
  k_prew<<<64, 256, 0, stream>>>(toA_w2, w2T);
  for (int l = 0; l < 2; ++l) {
    const float* xin = (l == 0) ? z_input : wx;
    k_ln_bu<<<512, 256, 0, stream>>>(xin, ln1_w, ln1_b, wBbr, wBbi, wfx, wbu, l);
    k_scan<<<16, 256, 0, stream>>>(wbu, wLbar, l);
    k_yproj<<<512, 256, 0, stream>>>(wbu, wCtr, wCti, wfx, Dp, wx, l);
    k_ff<<<512, 256, 0, stream>>>(wx, ln2_w, ln2_b, ff_enc, ff_dec, l);
  }
  k_toa1<<<512, 256, 0, stream>>>(wx, toA_w1, toA_b1, wh1);
  k_gemm_mfma<<<dim3(32, 128), 256, 0, stream>>>(w2T, wh1, toA_b2, mask_A, dt, wX);
  k_chunk<<<1024, 256, 0, stream>>>(wX);
  k_carry<<<32, 64, 0, stream>>>(z_input, wX, (float*)d_out);
  k_apply<<<1024, 256, 0, stream>>>(wX, (float*)d_out);
}

// Round 5
// 439.248 us; speedup vs baseline: 2.2026x; 1.2220x over previous
//
#include <hip/hip_runtime.h>

#define DI __device__ __forceinline__

typedef unsigned short u16;
typedef unsigned int u32;
typedef __attribute__((ext_vector_type(8))) short shortx8;
typedef __attribute__((ext_vector_type(4))) float floatx4;

DI float u2f(u32 x) { union { u32 u; float f; } v; v.u = x; return v.f; }
DI u32 f2u(float x) { union { u32 u; float f; } v; v.f = x; return v.u; }
DI float bflo(u32 w) { return u2f(w << 16); }
DI float bfhi(u32 w) { return u2f(w & 0xffff0000u); }
DI float bf1(u16 w) { return u2f(((u32)w) << 16); }
DI u16 f2bf(float f) {  // RNE
  u32 u = f2u(f);
  u32 r = (u + 0x7fffu + ((u >> 16) & 1u)) >> 16;
  return (u16)r;
}

DI float wsum64(float v) {
  v += __shfl_xor(v, 32);
  v += __shfl_xor(v, 16);
  v += __shfl_xor(v, 8);
  v += __shfl_xor(v, 4);
  v += __shfl_xor(v, 2);
  v += __shfl_xor(v, 1);
  return v;
}

DI float gelu_ex(float y) { return 0.5f * y * (1.0f + erff(y * 0.7071067811865476f)); }
DI float softplus_ex(float x) { return x > 0.f ? x + log1pf(expf(-x)) : log1pf(expf(x)); }

// ---------------- precompute: Lbar, Bbar ([h][p] planes), C transposed ([p][h] planes)
__global__ void k_pre(const float* __restrict__ Lam_re, const float* __restrict__ Lam_im,
                      const float* __restrict__ log_step,
                      const float* __restrict__ B_re, const float* __restrict__ B_im,
                      const float* __restrict__ C_re, const float* __restrict__ C_im,
                      float* __restrict__ wLbar, float* __restrict__ wBbr, float* __restrict__ wBbi,
                      float* __restrict__ wCtr, float* __restrict__ wCti) {
  int l = blockIdx.x;
  int p = threadIdx.x;  // 128
  int idx = l * 128 + p;
  float step = expf(log_step[idx]);
  float lre = -expf(Lam_re[idx]);
  float lim = Lam_im[idx];
  float er = expf(lre * step);
  float Lr = er * cosf(lim * step);
  float Li = er * sinf(lim * step);
  wLbar[idx * 2] = Lr;
  wLbar[idx * 2 + 1] = Li;
  float inv = 1.0f / (lre * lre + lim * lim);
  float nr = Lr - 1.0f, ni = Li;
  float qr = (nr * lre + ni * lim) * inv;
  float qi = (ni * lre - nr * lim) * inv;
  for (int h = 0; h < 64; ++h) {
    float br = B_re[idx * 64 + h], bim = B_im[idx * 64 + h];
    wBbr[(l * 64 + h) * 128 + p] = qr * br - qi * bim;
    wBbi[(l * 64 + h) * 128 + p] = qr * bim + qi * br;
    wCtr[idx * 64 + h] = C_re[(l * 64 + h) * 128 + p];
    wCti[idx * 64 + h] = C_im[(l * 64 + h) * 128 + p];
  }
}

// ---------------- transpose toA_w2 (128x4096 f32) -> w2T bf16 [4096][128]
__global__ __launch_bounds__(256) void k_prew(const float* __restrict__ w2, u16* __restrict__ w2T) {
  __shared__ float s[128][65];
  int t = threadIdx.x;
  int n0 = blockIdx.x * 64;
  for (int i = 0; i < 32; ++i) {
    int e = i * 256 + t;  // 0..8191
    int k = e >> 6, n = e & 63;
    s[k][n] = w2[(size_t)k * 4096 + n0 + n];
  }
  __syncthreads();
  for (int i = 0; i < 16; ++i) {
    int e = i * 256 + t;
    int n = e >> 6, kp = e & 63;
    u32 pk = (u32)f2bf(s[kp * 2][n]) | ((u32)f2bf(s[kp * 2 + 1][n]) << 16);
    ((u32*)w2T)[(size_t)(n0 + n) * 64 + kp] = pk;
  }
}

// ---------------- LN1 + Bu = einsum('ph,blh->blp')
__global__ __launch_bounds__(256) void k_ln_bu(
    const float* __restrict__ xin, const float* __restrict__ lnw, const float* __restrict__ lnb,
    const float* __restrict__ wBbr, const float* __restrict__ wBbi,
    float* __restrict__ fxg, float2* __restrict__ bu, int layer) {
  __shared__ float sbr[64 * 128];
  __shared__ float sbi[64 * 128];
  int t = threadIdx.x, w = t >> 6, lane = t & 63;
  {
    const float* br = wBbr + (size_t)layer * 8192;
    const float* bi = wBbi + (size_t)layer * 8192;
    for (int e = t; e < 8192; e += 256) { sbr[e] = br[e]; sbi[e] = bi[e]; }
  }
  float wv = lnw[layer * 64 + lane], bv = lnb[layer * 64 + lane];
  __syncthreads();
  int row0 = blockIdx.x * 32 + w * 8;
  float fxv[8];
#pragma unroll
  for (int rr = 0; rr < 8; ++rr) {
    size_t r = row0 + rr;
    float x = xin[r * 64 + lane];
    float mu = wsum64(x) * 0.015625f;
    float d = x - mu;
    float var = wsum64(d * d) * 0.015625f;
    float fx = d * rsqrtf(var + 1e-5f) * wv + bv;
    fxv[rr] = fx;
    fxg[r * 64 + lane] = fx;
  }
  float ar0[8] = {}, ai0[8] = {}, ar1[8] = {}, ai1[8] = {};
  for (int h = 0; h < 64; ++h) {
    float b0r = sbr[h * 128 + lane], b0i = sbi[h * 128 + lane];
    float b1r = sbr[h * 128 + lane + 64], b1i = sbi[h * 128 + lane + 64];
#pragma unroll
    for (int rr = 0; rr < 8; ++rr) {
      float f = __shfl(fxv[rr], h);
      ar0[rr] = fmaf(b0r, f, ar0[rr]);
      ai0[rr] = fmaf(b0i, f, ai0[rr]);
      ar1[rr] = fmaf(b1r, f, ar1[rr]);
      ai1[rr] = fmaf(b1i, f, ai1[rr]);
    }
  }
#pragma unroll
  for (int rr = 0; rr < 8; ++rr) {
    size_t r = row0 + rr;
    bu[r * 128 + lane] = make_float2(ar0[rr], ai0[rr]);
    bu[r * 128 + lane + 64] = make_float2(ar1[rr], ai1[rr]);
  }
}

// ---------------- diagonal complex inclusive scan over L, chunked 3-phase (in place)
// 256 blocks; block handles 16 chains (p) of one batch b, 16 chunks x 32 steps each.
__global__ __launch_bounds__(256) void k_scan(float2* __restrict__ bu,
                                              const float* __restrict__ wLbar, int layer) {
  __shared__ float2 carry[16][17];
  int t = threadIdx.x;
  int ck = t >> 4, chain = t & 15;
  int b = blockIdx.x >> 3;
  int p = (blockIdx.x & 7) * 16 + chain;
  float Lr = wLbar[(layer * 128 + p) * 2];
  float Li = wLbar[(layer * 128 + p) * 2 + 1];
  float2* ptr = bu + ((size_t)b * 512 * 128 + p);
  int l0 = ck * 32;
  // phase1: local chunk final (zero init), no stores
  float xr = 0.f, xi = 0.f;
#pragma unroll 4
  for (int i = 0; i < 32; ++i) {
    float2 v = ptr[(size_t)(l0 + i) * 128];
    float nr = fmaf(Lr, xr, fmaf(-Li, xi, v.x));
    float ni = fmaf(Lr, xi, fmaf(Li, xr, v.y));
    xr = nr; xi = ni;
  }
  carry[chain][ck] = make_float2(xr, xi);
  __syncthreads();
  // phase2: carry scan over 16 chunks, one thread per chain
  if (t < 16) {
    float ar = Lr, ai = Li;
#pragma unroll
    for (int s = 0; s < 5; ++s) {  // Le^32
      float nr = ar * ar - ai * ai;
      float ni = 2.f * ar * ai;
      ar = nr; ai = ni;
    }
    float cr = 0.f, ci2 = 0.f;
#pragma unroll
    for (int m = 0; m < 16; ++m) {
      float2 loc = carry[t][m];
      carry[t][m] = make_float2(cr, ci2);  // init state for chunk m
      float nr = fmaf(ar, cr, fmaf(-ai, ci2, loc.x));
      float ni = fmaf(ar, ci2, fmaf(ai, cr, loc.y));
      cr = nr; ci2 = ni;
    }
  }
  __syncthreads();
  // phase3: rescan with init carry, store
  float2 c0 = carry[chain][ck];
  xr = c0.x; xi = c0.y;
#pragma unroll 4
  for (int i = 0; i < 32; ++i) {
    float2 v = ptr[(size_t)(l0 + i) * 128];
    float nr = fmaf(Lr, xr, fmaf(-Li, xi, v.x));
    float ni = fmaf(Lr, xi, fmaf(Li, xr, v.y));
    xr = nr; xi = ni;
    ptr[(size_t)(l0 + i) * 128] = make_float2(xr, xi);
  }
}

// ---------------- y = 2*Re(C xs) + D*u ; x = gelu(y) + fx
__global__ __launch_bounds__(256) void k_yproj(
    const float2* __restrict__ xs, const float* __restrict__ wCtr, const float* __restrict__ wCti,
    const float* __restrict__ fxg, const float* __restrict__ Dp,
    float* __restrict__ xout, int layer) {
  __shared__ float ctr[64 * 64];
  __shared__ float cti[64 * 64];
  __shared__ float2 xsh[4][8][64];
  int t = threadIdx.x, w = t >> 6, lane = t & 63;
  int row0 = blockIdx.x * 32 + w * 8;
  float acc[8] = {};
  for (int ph = 0; ph < 2; ++ph) {
    __syncthreads();
    {
      const float* sr = wCtr + ((size_t)layer * 128 + ph * 64) * 64;
      const float* si = wCti + ((size_t)layer * 128 + ph * 64) * 64;
      for (int e = t; e < 4096; e += 256) { ctr[e] = sr[e]; cti[e] = si[e]; }
    }
#pragma unroll
    for (int rr = 0; rr < 8; ++rr) {
      size_t r = row0 + rr;
      xsh[w][rr][lane] = xs[r * 128 + ph * 64 + lane];
    }
    __syncthreads();
    for (int p = 0; p < 64; ++p) {
      float cr = ctr[p * 64 + lane];
      float ci = cti[p * 64 + lane];
#pragma unroll
      for (int rr = 0; rr < 8; ++rr) {
        float2 xv = xsh[w][rr][p];
        acc[rr] = fmaf(cr, xv.x, fmaf(-ci, xv.y, acc[rr]));
      }
    }
  }
  float Dv = Dp[layer * 64 + lane];
#pragma unroll
  for (int rr = 0; rr < 8; ++rr) {
    size_t r = row0 + rr;
    float u = fxg[r * 64 + lane];
    float y = 2.f * acc[rr] + Dv * u;
    xout[r * 64 + lane] = gelu_ex(y) + u;
  }
}

// ---------------- LN2 + GLU FFN + residual (in place on x)
__global__ __launch_bounds__(256) void k_ff(
    float* __restrict__ xio, const float* __restrict__ lnw, const float* __restrict__ lnb,
    const float* __restrict__ encw, const float* __restrict__ decw, int layer) {
  __shared__ float enc[64 * 128];
  __shared__ float dec[64 * 64];
  int t = threadIdx.x, w = t >> 6, lane = t & 63;
  {
    const float* e = encw + (size_t)layer * 8192;
    for (int i = t; i < 8192; i += 256) enc[i] = e[i];
    const float* d = decw + (size_t)layer * 4096;
    for (int i = t; i < 4096; i += 256) dec[i] = d[i];
  }
  float wv = lnw[layer * 64 + lane], bv = lnb[layer * 64 + lane];
  __syncthreads();
  int row0 = blockIdx.x * 32 + w * 8;
  float fx2v[8];
#pragma unroll
  for (int rr = 0; rr < 8; ++rr) {
    size_t r = row0 + rr;
    float x = xio[r * 64 + lane];
    float mu = wsum64(x) * 0.015625f;
    float d = x - mu;
    float var = wsum64(d * d) * 0.015625f;
    fx2v[rr] = d * rsqrtf(var + 1e-5f) * wv + bv;
  }
  float h0[8] = {}, h1v[8] = {};
  for (int h = 0; h < 64; ++h) {
    float e0 = enc[h * 128 + lane], e1 = enc[h * 128 + lane + 64];
#pragma unroll
    for (int rr = 0; rr < 8; ++rr) {
      float f = __shfl(fx2v[rr], h);
      h0[rr] = fmaf(e0, f, h0[rr]);
      h1v[rr] = fmaf(e1, f, h1v[rr]);
    }
  }
  float gv[8];
#pragma unroll
  for (int rr = 0; rr < 8; ++rr) gv[rr] = h0[rr] * gelu_ex(h1v[rr]);
  float o[8] = {};
  for (int j = 0; j < 64; ++j) {
    float dv = dec[j * 64 + lane];
#pragma unroll
    for (int rr = 0; rr < 8; ++rr) {
      float gj = __shfl(gv[rr], j);
      o[rr] = fmaf(dv, gj, o[rr]);
    }
  }
#pragma unroll
  for (int rr = 0; rr < 8; ++rr) {
    size_t r = row0 + rr;
    xio[r * 64 + lane] = o[rr] + fx2v[rr];
  }
}

// ---------------- h1 = softplus(x @ toA_w1 + b1) -> bf16 [16384][128]
__global__ __launch_bounds__(256) void k_toa1(
    const float* __restrict__ xin, const float* __restrict__ w1, const float* __restrict__ b1,
    u16* __restrict__ h1out) {
  __shared__ float w1s[64 * 128];
  int t = threadIdx.x, w = t >> 6, lane = t & 63;
  for (int i = t; i < 8192; i += 256) w1s[i] = w1[i];
  float bb0 = b1[lane], bb1 = b1[lane + 64];
  __syncthreads();
  int row0 = blockIdx.x * 32 + w * 8;
  float xv[8];
#pragma unroll
  for (int rr = 0; rr < 8; ++rr) xv[rr] = xin[(size_t)(row0 + rr) * 64 + lane];
  float a0[8] = {}, a1[8] = {};
  for (int h = 0; h < 64; ++h) {
    float e0 = w1s[h * 128 + lane], e1 = w1s[h * 128 + lane + 64];
#pragma unroll
    for (int rr = 0; rr < 8; ++rr) {
      float f = __shfl(xv[rr], h);
      a0[rr] = fmaf(e0, f, a0[rr]);
      a1[rr] = fmaf(e1, f, a1[rr]);
    }
  }
#pragma unroll
  for (int rr = 0; rr < 8; ++rr) {
    size_t r = row0 + rr;
    float v0 = softplus_ex(a0[rr] + bb0);  // k = lane
    float v1 = softplus_ex(a1[rr] + bb1);  // k = lane + 64
    int sl = (2 * lane) & 63;
    float ea = __shfl(v0, sl), eb = __shfl(v1, sl);
    float oa = __shfl(v0, sl + 1), ob = __shfl(v1, sl + 1);
    float lo = (lane < 32) ? ea : eb;
    float hi = (lane < 32) ? oa : ob;
    ((u32*)h1out)[r * 64 + lane] = (u32)f2bf(lo) | ((u32)f2bf(hi) << 16);
  }
}

// ---------------- MFMA big GEMM: X[m][n] = 0.5*dt[m]*(h1@w2 + b2)[m][n]*mask[n] -> bf16
__global__ __launch_bounds__(256) void k_gemm_mfma(
    const u16* __restrict__ w2T,  // [4096][128] bf16
    const u16* __restrict__ h1,   // [16384][128] bf16
    const float* __restrict__ b2, const float* __restrict__ mask,
    const float* __restrict__ dt, u16* __restrict__ Xout) {
  __shared__ __align__(16) u16 As[128 * 128];
  __shared__ __align__(16) u16 Bs[128 * 128];
  int t = threadIdx.x;
  int bn = blockIdx.x;  // 0..31
  int bm = blockIdx.y;  // 0..127
  {
    const u16* srcA = w2T + (size_t)(bn * 128) * 128;
    const u16* srcB = h1 + (size_t)(bm * 128) * 128;
#pragma unroll
    for (int i = 0; i < 8; ++i) {
      int r = i * 16 + (t >> 4);
      int gs = t & 15;
      int gsw = (gs & 8) | ((gs ^ r) & 7);
      uint4 va = *(const uint4*)(srcA + r * 128 + gs * 8);
      *(uint4*)(As + r * 128 + gsw * 8) = va;
      uint4 vb = *(const uint4*)(srcB + r * 128 + gs * 8);
      *(uint4*)(Bs + r * 128 + gsw * 8) = vb;
    }
  }
  __syncthreads();
  int w = t >> 6, l = t & 63;
  int n0 = (w & 1) * 64, m0 = (w >> 1) * 64;
  int lr = l & 15, kg = l >> 4;
  floatx4 acc[4][4];
#pragma unroll
  for (int i = 0; i < 4; ++i)
#pragma unroll
    for (int j = 0; j < 4; ++j) acc[i][j] = (floatx4){0.f, 0.f, 0.f, 0.f};
#pragma unroll
  for (int kk = 0; kk < 4; ++kk) {
    int g = kk * 4 + kg;
    shortx8 af[4], bf[4];
#pragma unroll
    for (int ni = 0; ni < 4; ++ni) {
      int r = n0 + ni * 16 + lr;
      int gsw = (g & 8) | ((g ^ r) & 7);
      af[ni] = *(const shortx8*)(As + r * 128 + gsw * 8);
    }
#pragma unroll
    for (int mi = 0; mi < 4; ++mi) {
      int r = m0 + mi * 16 + lr;
      int gsw = (g & 8) | ((g ^ r) & 7);
      bf[mi] = *(const shortx8*)(Bs + r * 128 + gsw * 8);
    }
#pragma unroll
    for (int ni = 0; ni < 4; ++ni)
#pragma unroll
      for (int mi = 0; mi < 4; ++mi)
        acc[ni][mi] = __builtin_amdgcn_mfma_f32_16x16x32_bf16(af[ni], bf[mi], acc[ni][mi], 0, 0, 0);
  }
  int q = (l >> 4) * 4;
#pragma unroll
  for (int mi = 0; mi < 4; ++mi) {
    int m = bm * 128 + m0 + mi * 16 + lr;
    float dv = 0.5f * dt[m];
#pragma unroll
    for (int ni = 0; ni < 4; ++ni) {
      int nl = n0 + ni * 16 + q;
      int n = bn * 128 + nl;
      float4 bb = *(const float4*)&b2[n];
      float4 mk = *(const float4*)&mask[n];
      floatx4 a = acc[ni][mi];
      float x0 = dv * (a[0] + bb.x) * mk.x;
      float x1 = dv * (a[1] + bb.y) * mk.y;
      float x2 = dv * (a[2] + bb.z) * mk.z;
      float x3 = dv * (a[3] + bb.w) * mk.w;
      u32 lo = (u32)f2bf(x0) | ((u32)f2bf(x1) << 16);
      u32 hi = (u32)f2bf(x2) | ((u32)f2bf(x3) << 16);
      *(uint2*)&Xout[(size_t)m * 4096 + n] = make_uint2(lo, hi);
    }
  }
}

// ---------------- fused chunk kernel v2: A_t = I + 2(X+X^2+X^3); R_j = A_{t0+j}...A_{t0};
// stores ST_j = (R_j - I)^T bf16 row-major IN PLACE over X_t. S^T master in registers.
__global__ __launch_bounds__(256, 4) void k_chunk(u16* __restrict__ Xg) {
  __shared__ __align__(16) u16 Xrm[4096];
  __shared__ __align__(16) u16 XTrm[4096];
  __shared__ __align__(16) u16 X2rm[4096];
  __shared__ __align__(16) u16 Erm[4096];
  __shared__ __align__(16) u16 STb[4096];
  int t = threadIdx.x, w = t >> 6, l = t & 63;
  int lr = l & 15, kg = l >> 4;
  int b = blockIdx.x >> 5, c = blockIdx.x & 31;
  u16* base = Xg + ((size_t)(b * 512 + c * 16)) * 4096;
  // S^T in regs (acc layout): sreg[j2] = S^T[p=j2*16+lr][q0=w*16+kg*4 ..+3]
  floatx4 sreg[4];
#pragma unroll
  for (int i = 0; i < 4; ++i) sreg[i] = (floatx4){0.f, 0.f, 0.f, 0.f};
  int r0 = (t >> 3) * 2, c0 = (t & 7) * 8, g0 = t & 7;
  int cw = t >> 3;  // u32 col index of XTrm for the scatter (= r0/2)
  uint4 pf0 = *(const uint4*)(base + r0 * 64 + c0);
  uint4 pf1 = *(const uint4*)(base + (r0 + 1) * 64 + c0);
  int q0 = w * 16 + kg * 4;
  for (int j = 0; j < 16; ++j) {
    u16* Xp = base + (size_t)j * 4096;
    __syncthreads();  // prev iter's m2 (Xrm/XTrm) and m3 (STb) reads complete
    // stage Xrm (swizzled granules)
    *(uint4*)(Xrm + r0 * 64 + ((g0 ^ r0) & 7) * 8) = pf0;
    *(uint4*)(Xrm + (r0 + 1) * 64 + ((g0 ^ (r0 + 1)) & 7) * 8) = pf1;
    // scatter own 2x8 block transposed into XTrm (u32 col-pairs, diagonal order)
    {
      const u16* a = (const u16*)&pf0;
      const u16* bq = (const u16*)&pf1;
#pragma unroll
      for (int i = 0; i < 8; ++i) {
        int ci = (i + t) & 7;
        int cc = c0 + ci;
        u32 val = (u32)a[ci] | ((u32)bq[ci] << 16);
        ((u32*)XTrm)[cc * 32 + (((cw >> 2) ^ cc) & 7) * 4 + (cw & 3)] = val;
      }
    }
    // pack STb = bf16(S^T) + I from sreg
#pragma unroll
    for (int j2 = 0; j2 < 4; ++j2) {
      int p = j2 * 16 + lr;
      floatx4 s = sreg[j2];
      float v0 = s[0] + ((p == q0 + 0) ? 1.f : 0.f);
      float v1 = s[1] + ((p == q0 + 1) ? 1.f : 0.f);
      float v2 = s[2] + ((p == q0 + 2) ? 1.f : 0.f);
      float v3 = s[3] + ((p == q0 + 3) ? 1.f : 0.f);
      u32 lo = (u32)f2bf(v0) | ((u32)f2bf(v1) << 16);
      u32 hi = (u32)f2bf(v2) | ((u32)f2bf(v3) << 16);
      *(uint2*)(STb + p * 64 + (((q0 >> 3) ^ p) & 7) * 8 + (q0 & 7)) = make_uint2(lo, hi);
    }
    // prefetch next X
    if (j < 15) {
      const u16* nx = Xp + 4096;
      pf0 = *(const uint4*)(nx + r0 * 64 + c0);
      pf1 = *(const uint4*)(nx + (r0 + 1) * 64 + c0);
    }
    __syncthreads();
    // hoist af = XTrm row qrow for g = kg, 4+kg (shared by m1, m2)
    int qrow = w * 16 + lr;
    shortx8 afx0 = *(const shortx8*)(XTrm + qrow * 64 + ((kg ^ qrow) & 7) * 8);
    shortx8 afx1 = *(const shortx8*)(XTrm + qrow * 64 + (((4 + kg) ^ qrow) & 7) * 8);
    // m1: X2 = X*X row-major
    {
      floatx4 acc[4];
#pragma unroll
      for (int i = 0; i < 4; ++i) acc[i] = (floatx4){0.f, 0.f, 0.f, 0.f};
#pragma unroll
      for (int kk = 0; kk < 2; ++kk) {
        int g = kk * 4 + kg;
        shortx8 af = kk ? afx1 : afx0;
#pragma unroll
        for (int j2 = 0; j2 < 4; ++j2) {
          int p = j2 * 16 + lr;
          shortx8 bf = *(const shortx8*)(Xrm + p * 64 + ((g ^ p) & 7) * 8);
          acc[j2] = __builtin_amdgcn_mfma_f32_16x16x32_bf16(af, bf, acc[j2], 0, 0, 0);
        }
      }
#pragma unroll
      for (int j2 = 0; j2 < 4; ++j2) {
        int p = j2 * 16 + lr;
        floatx4 a = acc[j2];
        u32 lo = (u32)f2bf(a[0]) | ((u32)f2bf(a[1]) << 16);
        u32 hi = (u32)f2bf(a[2]) | ((u32)f2bf(a[3]) << 16);
        *(uint2*)(X2rm + p * 64 + (((q0 >> 3) ^ p) & 7) * 8 + (q0 & 7)) = make_uint2(lo, hi);
      }
    }
    __syncthreads();
    // m2: X3 = X2*X row-major; E = 2(X + X2 + X3) -> Erm
    {
      floatx4 acc[4];
#pragma unroll
      for (int i = 0; i < 4; ++i) acc[i] = (floatx4){0.f, 0.f, 0.f, 0.f};
#pragma unroll
      for (int kk = 0; kk < 2; ++kk) {
        int g = kk * 4 + kg;
        shortx8 af = kk ? afx1 : afx0;
#pragma unroll
        for (int j2 = 0; j2 < 4; ++j2) {
          int p = j2 * 16 + lr;
          shortx8 bf = *(const shortx8*)(X2rm + p * 64 + ((g ^ p) & 7) * 8);
          acc[j2] = __builtin_amdgcn_mfma_f32_16x16x32_bf16(af, bf, acc[j2], 0, 0, 0);
        }
      }
#pragma unroll
      for (int j2 = 0; j2 < 4; ++j2) {
        int p = j2 * 16 + lr;
        int sw = (((q0 >> 3) ^ p) & 7) * 8 + (q0 & 7);
        uint2 xv = *(const uint2*)(Xrm + p * 64 + sw);
        uint2 x2v = *(const uint2*)(X2rm + p * 64 + sw);
        floatx4 a = acc[j2];
        float e0 = 2.f * (bflo(xv.x) + bflo(x2v.x) + a[0]);
        float e1 = 2.f * (bfhi(xv.x) + bfhi(x2v.x) + a[1]);
        float e2 = 2.f * (bflo(xv.y) + bflo(x2v.y) + a[2]);
        float e3 = 2.f * (bfhi(xv.y) + bfhi(x2v.y) + a[3]);
        u32 lo = (u32)f2bf(e0) | ((u32)f2bf(e1) << 16);
        u32 hi = (u32)f2bf(e2) | ((u32)f2bf(e3) << 16);
        *(uint2*)(Erm + p * 64 + sw) = make_uint2(lo, hi);
      }
    }
    __syncthreads();
    // m3: S^T += (E(I+S))^T = (I+S^T).E^T ; then writeout ST_j
    {
      floatx4 acc[4];
#pragma unroll
      for (int i = 0; i < 4; ++i) acc[i] = (floatx4){0.f, 0.f, 0.f, 0.f};
#pragma unroll
      for (int kk = 0; kk < 2; ++kk) {
        int g = kk * 4 + kg;
        shortx8 af = *(const shortx8*)(Erm + qrow * 64 + ((g ^ qrow) & 7) * 8);
#pragma unroll
        for (int j2 = 0; j2 < 4; ++j2) {
          int p = j2 * 16 + lr;
          shortx8 bf = *(const shortx8*)(STb + p * 64 + ((g ^ p) & 7) * 8);
          acc[j2] = __builtin_amdgcn_mfma_f32_16x16x32_bf16(af, bf, acc[j2], 0, 0, 0);
        }
      }
#pragma unroll
      for (int j2 = 0; j2 < 4; ++j2) {
        int p = j2 * 16 + lr;
        floatx4 a = acc[j2];
        floatx4 s = sreg[j2];
        s[0] += a[0]; s[1] += a[1]; s[2] += a[2]; s[3] += a[3];
        sreg[j2] = s;
        u32 lo = (u32)f2bf(s[0]) | ((u32)f2bf(s[1]) << 16);
        u32 hi = (u32)f2bf(s[2]) | ((u32)f2bf(s[3]) << 16);
        *(uint2*)(Xp + p * 64 + q0) = make_uint2(lo, hi);
      }
    }
  }
}

// ---------------- carry chain: z_{16(c+1)} = (I + S_15^{(c)}) z_{16c}; writes out[t=16c]
__global__ __launch_bounds__(64) void k_carry(const float* __restrict__ zin,
                                              const u16* __restrict__ R,
                                              float* __restrict__ out) {
  __shared__ __align__(16) u16 Ms[2][4096];
  int b = blockIdx.x, l = threadIdx.x;
  {
    const u16* M0 = R + ((size_t)(b * 512 + 15)) * 4096;
#pragma unroll
    for (int i = 0; i < 8; ++i) ((uint4*)Ms[0])[i * 64 + l] = ((const uint4*)M0)[i * 64 + l];
  }
  float cz = zin[(size_t)b * 512 * 64 + l];
  for (int c = 0; c < 32; ++c) {
    out[((size_t)(b * 512 + c * 16)) * 64 + l] = cz;
    uint4 nf0, nf1, nf2, nf3, nf4, nf5, nf6, nf7;
    if (c < 31) {
      const u16* Mn = R + ((size_t)(b * 512 + (c + 1) * 16 + 15)) * 4096;
      nf0 = ((const uint4*)Mn)[0 * 64 + l];
      nf1 = ((const uint4*)Mn)[1 * 64 + l];
      nf2 = ((const uint4*)Mn)[2 * 64 + l];
      nf3 = ((const uint4*)Mn)[3 * 64 + l];
      nf4 = ((const uint4*)Mn)[4 * 64 + l];
      nf5 = ((const uint4*)Mn)[5 * 64 + l];
      nf6 = ((const uint4*)Mn)[6 * 64 + l];
      nf7 = ((const uint4*)Mn)[7 * 64 + l];
    }
    const u16* M = Ms[c & 1];
    float a0 = 0.f, a1 = 0.f, a2 = 0.f, a3 = 0.f;
#pragma unroll
    for (int k = 0; k < 64; k += 4) {
      a0 = fmaf(bf1(M[(k + 0) * 64 + l]), __shfl(cz, k + 0), a0);
      a1 = fmaf(bf1(M[(k + 1) * 64 + l]), __shfl(cz, k + 1), a1);
      a2 = fmaf(bf1(M[(k + 2) * 64 + l]), __shfl(cz, k + 2), a2);
      a3 = fmaf(bf1(M[(k + 3) * 64 + l]), __shfl(cz, k + 3), a3);
    }
    cz += (a0 + a1) + (a2 + a3);
    if (c < 31) {
      uint4* d = (uint4*)Ms[(c + 1) & 1];
      d[0 * 64 + l] = nf0; d[1 * 64 + l] = nf1; d[2 * 64 + l] = nf2; d[3 * 64 + l] = nf3;
      d[4 * 64 + l] = nf4; d[5 * 64 + l] = nf5; d[6 * 64 + l] = nf6; d[7 * 64 + l] = nf7;
    }
  }
}

// ---------------- apply: z_{16c+j+1} = (I + S_j) z_{16c}, j = 0..14 (global-direct, L3-hot)
__global__ __launch_bounds__(256) void k_apply(const u16* __restrict__ R,
                                               float* __restrict__ out) {
  __shared__ float carr[64];
  int t = threadIdx.x, w = t >> 6, l = t & 63;
  int b = blockIdx.x >> 5, c = blockIdx.x & 31;
  const u16* Rb = R + ((size_t)(b * 512 + c * 16)) * 4096;
  if (t < 64) carr[t] = out[((size_t)(b * 512 + c * 16)) * 64 + t];
  __syncthreads();
  for (int j = w; j < 15; j += 4) {
    const u16* M = Rb + (size_t)j * 4096;
    float a0 = 0.f, a1 = 0.f, a2 = 0.f, a3 = 0.f;
#pragma unroll
    for (int k = 0; k < 64; k += 4) {
      a0 = fmaf(bf1(M[(k + 0) * 64 + l]), carr[k + 0], a0);
      a1 = fmaf(bf1(M[(k + 1) * 64 + l]), carr[k + 1], a1);
      a2 = fmaf(bf1(M[(k + 2) * 64 + l]), carr[k + 2], a2);
      a3 = fmaf(bf1(M[(k + 3) * 64 + l]), carr[k + 3], a3);
    }
    float zo = carr[l] + ((a0 + a1) + (a2 + a3));
    out[((size_t)(b * 512 + c * 16 + j + 1)) * 64 + l] = zo;
  }
}

extern "C" void kernel_launch(void* const* d_in, const int* in_sizes, int n_in,
                              void* d_out, int out_size, void* d_ws, size_t ws_size,
                              hipStream_t stream) {
  const float* z_input  = (const float*)d_in[0];
  const float* dt       = (const float*)d_in[1];
  const float* ln1_w    = (const float*)d_in[2];
  const float* ln1_b    = (const float*)d_in[3];
  const float* Lam_re   = (const float*)d_in[4];
  const float* Lam_im   = (const float*)d_in[5];
  const float* B_re     = (const float*)d_in[6];
  const float* B_im     = (const float*)d_in[7];
  const float* C_re     = (const float*)d_in[8];
  const float* C_im     = (const float*)d_in[9];
  const float* Dp       = (const float*)d_in[10];
  const float* log_step = (const float*)d_in[11];
  const float* ln2_w    = (const float*)d_in[12];
  const float* ln2_b    = (const float*)d_in[13];
  const float* ff_enc   = (const float*)d_in[14];
  const float* ff_dec   = (const float*)d_in[15];
  const float* toA_w1   = (const float*)d_in[16];
  const float* toA_b1   = (const float*)d_in[17];
  const float* toA_w2   = (const float*)d_in[18];
  const float* toA_b2   = (const float*)d_in[19];
  const float* mask_A   = (const float*)d_in[20];

  char* ws = (char*)d_ws;
  float* wLbar = (float*)(ws + 0);
  float* wBbr  = (float*)(ws + 2048);
  float* wBbi  = (float*)(ws + 67584);
  float* wCtr  = (float*)(ws + 133120);
  float* wCti  = (float*)(ws + 198656);
  float* wfx   = (float*)(ws + 264192);
  float* wx    = (float*)(ws + 4458496);
  float2* wbu  = (float2*)(ws + 8652800);
  u16* wh1     = (u16*)(ws + 25430016);   // [16384][128] bf16
  u16* w2T     = (u16*)(ws + 29624320);   // [4096][128] bf16
  u16* wX      = (u16*)(ws + 30672896);   // [16384][4096] bf16 (X, then ST in place)
  if (ws_size < 164890624ull) return;

  k_pre<<<2, 128, 0, stream>>>(Lam_re, Lam_im, log_step, B_re, B_im, C_re, C_im,
                               wLbar, wBbr, wBbi, wCtr, wCti);
  k_prew<<<64, 256, 0, stream>>>(toA_w2, w2T);
  for (int l = 0; l < 2; ++l) {
    const float* xin = (l == 0) ? z_input : wx;
    k_ln_bu<<<512, 256, 0, stream>>>(xin, ln1_w, ln1_b, wBbr, wBbi, wfx, wbu, l);
    k_scan<<<256, 256, 0, stream>>>(wbu, wLbar, l);
    k_yproj<<<512, 256, 0, stream>>>(wbu, wCtr, wCti, wfx, Dp, wx, l);
    k_ff<<<512, 256, 0, stream>>>(wx, ln2_w, ln2_b, ff_enc, ff_dec, l);
  }
  k_toa1<<<512, 256, 0, stream>>>(wx, toA_w1, toA_b1, wh1);
  k_gemm_mfma<<<dim3(32, 128), 256, 0, stream>>>(w2T, wh1, toA_b2, mask_A, dt, wX);
  k_chunk<<<1024, 256, 0, stream>>>(wX);
  k_carry<<<32, 64, 0, stream>>>(z_input, wX, (float*)d_out);
  k_apply<<<1024, 256, 0, stream>>>(wX, (float*)d_out);
}

// Round 6
// 396.887 us; speedup vs baseline: 2.4377x; 1.1067x over previous
//
#include <hip/hip_runtime.h>

#define DI __device__ __forceinline__

typedef unsigned short u16;
typedef unsigned int u32;
typedef __attribute__((ext_vector_type(8))) short shortx8;
typedef __attribute__((ext_vector_type(4))) float floatx4;

DI float u2f(u32 x) { union { u32 u; float f; } v; v.u = x; return v.f; }
DI u32 f2u(float x) { union { u32 u; float f; } v; v.f = x; return v.u; }
DI float bflo(u32 w) { return u2f(w << 16); }
DI float bfhi(u32 w) { return u2f(w & 0xffff0000u); }
DI float bf1(u16 w) { return u2f(((u32)w) << 16); }
DI u16 f2bf(float f) {  // RNE
  u32 u = f2u(f);
  u32 r = (u + 0x7fffu + ((u >> 16) & 1u)) >> 16;
  return (u16)r;
}

DI float wsum64(float v) {
  v += __shfl_xor(v, 32);
  v += __shfl_xor(v, 16);
  v += __shfl_xor(v, 8);
  v += __shfl_xor(v, 4);
  v += __shfl_xor(v, 2);
  v += __shfl_xor(v, 1);
  return v;
}

DI float gelu_ex(float y) { return 0.5f * y * (1.0f + erff(y * 0.7071067811865476f)); }
DI float softplus_ex(float x) { return x > 0.f ? x + log1pf(expf(-x)) : log1pf(expf(x)); }

// ---------------- precompute: Lbar, Bbar ([h][p] planes), C transposed ([p][h] planes)
__global__ void k_pre(const float* __restrict__ Lam_re, const float* __restrict__ Lam_im,
                      const float* __restrict__ log_step,
                      const float* __restrict__ B_re, const float* __restrict__ B_im,
                      const float* __restrict__ C_re, const float* __restrict__ C_im,
                      float* __restrict__ wLbar, float* __restrict__ wBbr, float* __restrict__ wBbi,
                      float* __restrict__ wCtr, float* __restrict__ wCti) {
  int l = blockIdx.x;
  int p = threadIdx.x;  // 128
  int idx = l * 128 + p;
  float step = expf(log_step[idx]);
  float lre = -expf(Lam_re[idx]);
  float lim = Lam_im[idx];
  float er = expf(lre * step);
  float Lr = er * cosf(lim * step);
  float Li = er * sinf(lim * step);
  wLbar[idx * 2] = Lr;
  wLbar[idx * 2 + 1] = Li;
  float inv = 1.0f / (lre * lre + lim * lim);
  float nr = Lr - 1.0f, ni = Li;
  float qr = (nr * lre + ni * lim) * inv;
  float qi = (ni * lre - nr * lim) * inv;
  for (int h = 0; h < 64; ++h) {
    float br = B_re[idx * 64 + h], bim = B_im[idx * 64 + h];
    wBbr[(l * 64 + h) * 128 + p] = qr * br - qi * bim;
    wBbi[(l * 64 + h) * 128 + p] = qr * bim + qi * br;
    wCtr[idx * 64 + h] = C_re[(l * 64 + h) * 128 + p];
    wCti[idx * 64 + h] = C_im[(l * 64 + h) * 128 + p];
  }
}

// ---------------- transpose toA_w2 (128x4096 f32) -> w2T bf16 [4096][128]
__global__ __launch_bounds__(256) void k_prew(const float* __restrict__ w2, u16* __restrict__ w2T) {
  __shared__ float s[128][65];
  int t = threadIdx.x;
  int n0 = blockIdx.x * 64;
  for (int i = 0; i < 32; ++i) {
    int e = i * 256 + t;  // 0..8191
    int k = e >> 6, n = e & 63;
    s[k][n] = w2[(size_t)k * 4096 + n0 + n];
  }
  __syncthreads();
  for (int i = 0; i < 16; ++i) {
    int e = i * 256 + t;
    int n = e >> 6, kp = e & 63;
    u32 pk = (u32)f2bf(s[kp * 2][n]) | ((u32)f2bf(s[kp * 2 + 1][n]) << 16);
    ((u32*)w2T)[(size_t)(n0 + n) * 64 + kp] = pk;
  }
}

// ---------------- LN1 + Bu = einsum('ph,blh->blp')
__global__ __launch_bounds__(256) void k_ln_bu(
    const float* __restrict__ xin, const float* __restrict__ lnw, const float* __restrict__ lnb,
    const float* __restrict__ wBbr, const float* __restrict__ wBbi,
    float* __restrict__ fxg, float2* __restrict__ bu, int layer) {
  __shared__ float sbr[64 * 128];
  __shared__ float sbi[64 * 128];
  int t = threadIdx.x, w = t >> 6, lane = t & 63;
  {
    const float* br = wBbr + (size_t)layer * 8192;
    const float* bi = wBbi + (size_t)layer * 8192;
    for (int e = t; e < 8192; e += 256) { sbr[e] = br[e]; sbi[e] = bi[e]; }
  }
  float wv = lnw[layer * 64 + lane], bv = lnb[layer * 64 + lane];
  __syncthreads();
  int row0 = blockIdx.x * 32 + w * 8;
  float fxv[8];
#pragma unroll
  for (int rr = 0; rr < 8; ++rr) {
    size_t r = row0 + rr;
    float x = xin[r * 64 + lane];
    float mu = wsum64(x) * 0.015625f;
    float d = x - mu;
    float var = wsum64(d * d) * 0.015625f;
    float fx = d * rsqrtf(var + 1e-5f) * wv + bv;
    fxv[rr] = fx;
    fxg[r * 64 + lane] = fx;
  }
  float ar0[8] = {}, ai0[8] = {}, ar1[8] = {}, ai1[8] = {};
  for (int h = 0; h < 64; ++h) {
    float b0r = sbr[h * 128 + lane], b0i = sbi[h * 128 + lane];
    float b1r = sbr[h * 128 + lane + 64], b1i = sbi[h * 128 + lane + 64];
#pragma unroll
    for (int rr = 0; rr < 8; ++rr) {
      float f = __shfl(fxv[rr], h);
      ar0[rr] = fmaf(b0r, f, ar0[rr]);
      ai0[rr] = fmaf(b0i, f, ai0[rr]);
      ar1[rr] = fmaf(b1r, f, ar1[rr]);
      ai1[rr] = fmaf(b1i, f, ai1[rr]);
    }
  }
#pragma unroll
  for (int rr = 0; rr < 8; ++rr) {
    size_t r = row0 + rr;
    bu[r * 128 + lane] = make_float2(ar0[rr], ai0[rr]);
    bu[r * 128 + lane + 64] = make_float2(ar1[rr], ai1[rr]);
  }
}

// ---------------- diagonal complex inclusive scan over L, chunked 3-phase (in place)
__global__ __launch_bounds__(256) void k_scan(float2* __restrict__ bu,
                                              const float* __restrict__ wLbar, int layer) {
  __shared__ float2 carry[16][17];
  int t = threadIdx.x;
  int ck = t >> 4, chain = t & 15;
  int b = blockIdx.x >> 3;
  int p = (blockIdx.x & 7) * 16 + chain;
  float Lr = wLbar[(layer * 128 + p) * 2];
  float Li = wLbar[(layer * 128 + p) * 2 + 1];
  float2* ptr = bu + ((size_t)b * 512 * 128 + p);
  int l0 = ck * 32;
  float xr = 0.f, xi = 0.f;
#pragma unroll 4
  for (int i = 0; i < 32; ++i) {
    float2 v = ptr[(size_t)(l0 + i) * 128];
    float nr = fmaf(Lr, xr, fmaf(-Li, xi, v.x));
    float ni = fmaf(Lr, xi, fmaf(Li, xr, v.y));
    xr = nr; xi = ni;
  }
  carry[chain][ck] = make_float2(xr, xi);
  __syncthreads();
  if (t < 16) {
    float ar = Lr, ai = Li;
#pragma unroll
    for (int s = 0; s < 5; ++s) {
      float nr = ar * ar - ai * ai;
      float ni = 2.f * ar * ai;
      ar = nr; ai = ni;
    }
    float cr = 0.f, ci2 = 0.f;
#pragma unroll
    for (int m = 0; m < 16; ++m) {
      float2 loc = carry[t][m];
      carry[t][m] = make_float2(cr, ci2);
      float nr = fmaf(ar, cr, fmaf(-ai, ci2, loc.x));
      float ni = fmaf(ar, ci2, fmaf(ai, cr, loc.y));
      cr = nr; ci2 = ni;
    }
  }
  __syncthreads();
  float2 c0 = carry[chain][ck];
  xr = c0.x; xi = c0.y;
#pragma unroll 4
  for (int i = 0; i < 32; ++i) {
    float2 v = ptr[(size_t)(l0 + i) * 128];
    float nr = fmaf(Lr, xr, fmaf(-Li, xi, v.x));
    float ni = fmaf(Lr, xi, fmaf(Li, xr, v.y));
    xr = nr; xi = ni;
    ptr[(size_t)(l0 + i) * 128] = make_float2(xr, xi);
  }
}

// ---------------- y = 2*Re(C xs) + D*u ; x = gelu(y) + fx
__global__ __launch_bounds__(256) void k_yproj(
    const float2* __restrict__ xs, const float* __restrict__ wCtr, const float* __restrict__ wCti,
    const float* __restrict__ fxg, const float* __restrict__ Dp,
    float* __restrict__ xout, int layer) {
  __shared__ float ctr[64 * 64];
  __shared__ float cti[64 * 64];
  __shared__ float2 xsh[4][8][64];
  int t = threadIdx.x, w = t >> 6, lane = t & 63;
  int row0 = blockIdx.x * 32 + w * 8;
  float acc[8] = {};
  for (int ph = 0; ph < 2; ++ph) {
    __syncthreads();
    {
      const float* sr = wCtr + ((size_t)layer * 128 + ph * 64) * 64;
      const float* si = wCti + ((size_t)layer * 128 + ph * 64) * 64;
      for (int e = t; e < 4096; e += 256) { ctr[e] = sr[e]; cti[e] = si[e]; }
    }
#pragma unroll
    for (int rr = 0; rr < 8; ++rr) {
      size_t r = row0 + rr;
      xsh[w][rr][lane] = xs[r * 128 + ph * 64 + lane];
    }
    __syncthreads();
    for (int p = 0; p < 64; ++p) {
      float cr = ctr[p * 64 + lane];
      float ci = cti[p * 64 + lane];
#pragma unroll
      for (int rr = 0; rr < 8; ++rr) {
        float2 xv = xsh[w][rr][p];
        acc[rr] = fmaf(cr, xv.x, fmaf(-ci, xv.y, acc[rr]));
      }
    }
  }
  float Dv = Dp[layer * 64 + lane];
#pragma unroll
  for (int rr = 0; rr < 8; ++rr) {
    size_t r = row0 + rr;
    float u = fxg[r * 64 + lane];
    float y = 2.f * acc[rr] + Dv * u;
    xout[r * 64 + lane] = gelu_ex(y) + u;
  }
}

// ---------------- LN2 + GLU FFN + residual (in place on x)
__global__ __launch_bounds__(256) void k_ff(
    float* __restrict__ xio, const float* __restrict__ lnw, const float* __restrict__ lnb,
    const float* __restrict__ encw, const float* __restrict__ decw, int layer) {
  __shared__ float enc[64 * 128];
  __shared__ float dec[64 * 64];
  int t = threadIdx.x, w = t >> 6, lane = t & 63;
  {
    const float* e = encw + (size_t)layer * 8192;
    for (int i = t; i < 8192; i += 256) enc[i] = e[i];
    const float* d = decw + (size_t)layer * 4096;
    for (int i = t; i < 4096; i += 256) dec[i] = d[i];
  }
  float wv = lnw[layer * 64 + lane], bv = lnb[layer * 64 + lane];
  __syncthreads();
  int row0 = blockIdx.x * 32 + w * 8;
  float fx2v[8];
#pragma unroll
  for (int rr = 0; rr < 8; ++rr) {
    size_t r = row0 + rr;
    float x = xio[r * 64 + lane];
    float mu = wsum64(x) * 0.015625f;
    float d = x - mu;
    float var = wsum64(d * d) * 0.015625f;
    fx2v[rr] = d * rsqrtf(var + 1e-5f) * wv + bv;
  }
  float h0[8] = {}, h1v[8] = {};
  for (int h = 0; h < 64; ++h) {
    float e0 = enc[h * 128 + lane], e1 = enc[h * 128 + lane + 64];
#pragma unroll
    for (int rr = 0; rr < 8; ++rr) {
      float f = __shfl(fx2v[rr], h);
      h0[rr] = fmaf(e0, f, h0[rr]);
      h1v[rr] = fmaf(e1, f, h1v[rr]);
    }
  }
  float gv[8];
#pragma unroll
  for (int rr = 0; rr < 8; ++rr) gv[rr] = h0[rr] * gelu_ex(h1v[rr]);
  float o[8] = {};
  for (int j = 0; j < 64; ++j) {
    float dv = dec[j * 64 + lane];
#pragma unroll
    for (int rr = 0; rr < 8; ++rr) {
      float gj = __shfl(gv[rr], j);
      o[rr] = fmaf(dv, gj, o[rr]);
    }
  }
#pragma unroll
  for (int rr = 0; rr < 8; ++rr) {
    size_t r = row0 + rr;
    xio[r * 64 + lane] = o[rr] + fx2v[rr];
  }
}

// ---------------- h1 = softplus(x @ toA_w1 + b1) -> bf16 [16384][128]
__global__ __launch_bounds__(256) void k_toa1(
    const float* __restrict__ xin, const float* __restrict__ w1, const float* __restrict__ b1,
    u16* __restrict__ h1out) {
  __shared__ float w1s[64 * 128];
  int t = threadIdx.x, w = t >> 6, lane = t & 63;
  for (int i = t; i < 8192; i += 256) w1s[i] = w1[i];
  float bb0 = b1[lane], bb1 = b1[lane + 64];
  __syncthreads();
  int row0 = blockIdx.x * 32 + w * 8;
  float xv[8];
#pragma unroll
  for (int rr = 0; rr < 8; ++rr) xv[rr] = xin[(size_t)(row0 + rr) * 64 + lane];
  float a0[8] = {}, a1[8] = {};
  for (int h = 0; h < 64; ++h) {
    float e0 = w1s[h * 128 + lane], e1 = w1s[h * 128 + lane + 64];
#pragma unroll
    for (int rr = 0; rr < 8; ++rr) {
      float f = __shfl(xv[rr], h);
      a0[rr] = fmaf(e0, f, a0[rr]);
      a1[rr] = fmaf(e1, f, a1[rr]);
    }
  }
#pragma unroll
  for (int rr = 0; rr < 8; ++rr) {
    size_t r = row0 + rr;
    float v0 = softplus_ex(a0[rr] + bb0);
    float v1 = softplus_ex(a1[rr] + bb1);
    int sl = (2 * lane) & 63;
    float ea = __shfl(v0, sl), eb = __shfl(v1, sl);
    float oa = __shfl(v0, sl + 1), ob = __shfl(v1, sl + 1);
    float lo = (lane < 32) ? ea : eb;
    float hi = (lane < 32) ? oa : ob;
    ((u32*)h1out)[r * 64 + lane] = (u32)f2bf(lo) | ((u32)f2bf(hi) << 16);
  }
}

// ---------------- MFMA big GEMM: X[m][n] = 0.5*dt[m]*(h1@w2 + b2)[m][n]*mask[n] -> bf16
// epilogue staged through LDS for line-complete coalesced global writes.
__global__ __launch_bounds__(256) void k_gemm_mfma(
    const u16* __restrict__ w2T,  // [4096][128] bf16
    const u16* __restrict__ h1,   // [16384][128] bf16
    const float* __restrict__ b2, const float* __restrict__ mask,
    const float* __restrict__ dt, u16* __restrict__ Xout) {
  __shared__ __align__(16) u16 As[128 * 128];
  __shared__ __align__(16) u16 Bs[128 * 128];
  int t = threadIdx.x;
  int bn = blockIdx.x;  // 0..31
  int bm = blockIdx.y;  // 0..127
  {
    const u16* srcA = w2T + (size_t)(bn * 128) * 128;
    const u16* srcB = h1 + (size_t)(bm * 128) * 128;
#pragma unroll
    for (int i = 0; i < 8; ++i) {
      int r = i * 16 + (t >> 4);
      int gs = t & 15;
      int gsw = (gs & 8) | ((gs ^ r) & 7);
      uint4 va = *(const uint4*)(srcA + r * 128 + gs * 8);
      *(uint4*)(As + r * 128 + gsw * 8) = va;
      uint4 vb = *(const uint4*)(srcB + r * 128 + gs * 8);
      *(uint4*)(Bs + r * 128 + gsw * 8) = vb;
    }
  }
  __syncthreads();
  int w = t >> 6, l = t & 63;
  int n0 = (w & 1) * 64, m0 = (w >> 1) * 64;
  int lr = l & 15, kg = l >> 4;
  floatx4 acc[4][4];
#pragma unroll
  for (int i = 0; i < 4; ++i)
#pragma unroll
    for (int j = 0; j < 4; ++j) acc[i][j] = (floatx4){0.f, 0.f, 0.f, 0.f};
#pragma unroll
  for (int kk = 0; kk < 4; ++kk) {
    int g = kk * 4 + kg;
    shortx8 af[4], bf[4];
#pragma unroll
    for (int ni = 0; ni < 4; ++ni) {
      int r = n0 + ni * 16 + lr;
      int gsw = (g & 8) | ((g ^ r) & 7);
      af[ni] = *(const shortx8*)(As + r * 128 + gsw * 8);
    }
#pragma unroll
    for (int mi = 0; mi < 4; ++mi) {
      int r = m0 + mi * 16 + lr;
      int gsw = (g & 8) | ((g ^ r) & 7);
      bf[mi] = *(const shortx8*)(Bs + r * 128 + gsw * 8);
    }
#pragma unroll
    for (int ni = 0; ni < 4; ++ni)
#pragma unroll
      for (int mi = 0; mi < 4; ++mi)
        acc[ni][mi] = __builtin_amdgcn_mfma_f32_16x16x32_bf16(af[ni], bf[mi], acc[ni][mi], 0, 0, 0);
  }
  __syncthreads();  // done reading As/Bs; reuse As as output stage
  int q = (l >> 4) * 4;
#pragma unroll
  for (int mi = 0; mi < 4; ++mi) {
    int ml = m0 + mi * 16 + lr;
    int m = bm * 128 + ml;
    float dv = 0.5f * dt[m];
#pragma unroll
    for (int ni = 0; ni < 4; ++ni) {
      int nl = n0 + ni * 16 + q;
      int n = bn * 128 + nl;
      float4 bb = *(const float4*)&b2[n];
      float4 mk = *(const float4*)&mask[n];
      floatx4 a = acc[ni][mi];
      float x0 = dv * (a[0] + bb.x) * mk.x;
      float x1 = dv * (a[1] + bb.y) * mk.y;
      float x2 = dv * (a[2] + bb.z) * mk.z;
      float x3 = dv * (a[3] + bb.w) * mk.w;
      u32 lo = (u32)f2bf(x0) | ((u32)f2bf(x1) << 16);
      u32 hi = (u32)f2bf(x2) | ((u32)f2bf(x3) << 16);
      int g = nl >> 3;
      int gsw = (g & 8) | ((g ^ ml) & 7);
      *(uint2*)(As + ml * 128 + gsw * 8 + (nl & 7)) = make_uint2(lo, hi);
    }
  }
  __syncthreads();
  // coalesced writeout: 8 lanes cover one full 128B line per instruction
  int seg = t & 7;
#pragma unroll
  for (int pp = 0; pp < 4; ++pp) {
    int r = pp * 32 + (t >> 3);
#pragma unroll
    for (int ii = 0; ii < 2; ++ii) {
      int g = seg * 2 + ii;
      int gsw = (g & 8) | ((g ^ r) & 7);
      uint4 v = *(const uint4*)(As + r * 128 + gsw * 8);
      *(uint4*)&Xout[(size_t)(bm * 128 + r) * 4096 + bn * 128 + g * 8] = v;
    }
  }
}

// ---------------- fused chunk kernel v3: A_t = I + 2(X+X^2); R_j = A_{t0+j}...A_{t0};
// stores ST_j = (R_j - I)^T bf16 row-major IN PLACE over X_t. S^T master in registers.
// Writeout staged through SOut LDS -> line-complete coalesced stores, overlapped.
__global__ __launch_bounds__(256, 4) void k_chunk(u16* __restrict__ Xg) {
  __shared__ __align__(16) u16 Xrm[4096];
  __shared__ __align__(16) u16 XTrm[4096];
  __shared__ __align__(16) u16 Erm[4096];
  __shared__ __align__(16) u16 STb[4096];
  __shared__ __align__(16) u16 SOut[4096];
  int t = threadIdx.x, w = t >> 6, l = t & 63;
  int lr = l & 15, kg = l >> 4;
  int b = blockIdx.x >> 5, c = blockIdx.x & 31;
  u16* base = Xg + ((size_t)(b * 512 + c * 16)) * 4096;
  floatx4 sreg[4];
#pragma unroll
  for (int i = 0; i < 4; ++i) sreg[i] = (floatx4){0.f, 0.f, 0.f, 0.f};
  int r0 = (t >> 3) * 2, c0 = (t & 7) * 8, g0 = t & 7;
  int cw = t >> 3;
  uint4 pf0 = *(const uint4*)(base + r0 * 64 + c0);
  uint4 pf1 = *(const uint4*)(base + (r0 + 1) * 64 + c0);
  int q0 = w * 16 + kg * 4;
  int qrow = w * 16 + lr;
  int wr = t >> 2, wg = (t & 3) * 2;  // writeout: row, granule pair
  for (int j = 0; j < 16; ++j) {
    __syncthreads();  // SOut(j-1) ready; Xrm/XTrm/STb free
    // overlapped coalesced writeout of S_{j-1}
    if (j > 0) {
      u16* Xprev = base + (size_t)(j - 1) * 4096;
      uint4 v0 = *(const uint4*)(SOut + wr * 64 + (((wg + 0) ^ wr) & 7) * 8);
      uint4 v1 = *(const uint4*)(SOut + wr * 64 + (((wg + 1) ^ wr) & 7) * 8);
      *(uint4*)(Xprev + wr * 64 + wg * 8) = v0;
      *(uint4*)(Xprev + wr * 64 + wg * 8 + 8) = v1;
    }
    // stage Xrm (swizzled granules)
    *(uint4*)(Xrm + r0 * 64 + ((g0 ^ r0) & 7) * 8) = pf0;
    *(uint4*)(Xrm + (r0 + 1) * 64 + ((g0 ^ (r0 + 1)) & 7) * 8) = pf1;
    // scatter own 2x8 block transposed into XTrm (u32 col-pairs, diagonal order)
    {
      const u16* a = (const u16*)&pf0;
      const u16* bq = (const u16*)&pf1;
#pragma unroll
      for (int i = 0; i < 8; ++i) {
        int ci = (i + t) & 7;
        int cc = c0 + ci;
        u32 val = (u32)a[ci] | ((u32)bq[ci] << 16);
        ((u32*)XTrm)[cc * 32 + (((cw >> 2) ^ cc) & 7) * 4 + (cw & 3)] = val;
      }
    }
    // pack STb = bf16(S^T) + I from sreg
#pragma unroll
    for (int j2 = 0; j2 < 4; ++j2) {
      int p = j2 * 16 + lr;
      floatx4 s = sreg[j2];
      float v0 = s[0] + ((p == q0 + 0) ? 1.f : 0.f);
      float v1 = s[1] + ((p == q0 + 1) ? 1.f : 0.f);
      float v2 = s[2] + ((p == q0 + 2) ? 1.f : 0.f);
      float v3 = s[3] + ((p == q0 + 3) ? 1.f : 0.f);
      u32 lo = (u32)f2bf(v0) | ((u32)f2bf(v1) << 16);
      u32 hi = (u32)f2bf(v2) | ((u32)f2bf(v3) << 16);
      *(uint2*)(STb + p * 64 + (((q0 >> 3) ^ p) & 7) * 8 + (q0 & 7)) = make_uint2(lo, hi);
    }
    // prefetch next X
    if (j < 15) {
      const u16* nx = base + (size_t)(j + 1) * 4096;
      pf0 = *(const uint4*)(nx + r0 * 64 + c0);
      pf1 = *(const uint4*)(nx + (r0 + 1) * 64 + c0);
    }
    __syncthreads();
    // m1: X2 = X*X ; E = 2(X + X2) -> Erm
    shortx8 afx0 = *(const shortx8*)(XTrm + qrow * 64 + ((kg ^ qrow) & 7) * 8);
    shortx8 afx1 = *(const shortx8*)(XTrm + qrow * 64 + (((4 + kg) ^ qrow) & 7) * 8);
    {
      floatx4 acc[4];
#pragma unroll
      for (int i = 0; i < 4; ++i) acc[i] = (floatx4){0.f, 0.f, 0.f, 0.f};
#pragma unroll
      for (int kk = 0; kk < 2; ++kk) {
        int g = kk * 4 + kg;
        shortx8 af = kk ? afx1 : afx0;
#pragma unroll
        for (int j2 = 0; j2 < 4; ++j2) {
          int p = j2 * 16 + lr;
          shortx8 bf = *(const shortx8*)(Xrm + p * 64 + ((g ^ p) & 7) * 8);
          acc[j2] = __builtin_amdgcn_mfma_f32_16x16x32_bf16(af, bf, acc[j2], 0, 0, 0);
        }
      }
#pragma unroll
      for (int j2 = 0; j2 < 4; ++j2) {
        int p = j2 * 16 + lr;
        int sw = (((q0 >> 3) ^ p) & 7) * 8 + (q0 & 7);
        uint2 xv = *(const uint2*)(Xrm + p * 64 + sw);
        floatx4 a = acc[j2];
        float e0 = 2.f * (bflo(xv.x) + a[0]);
        float e1 = 2.f * (bfhi(xv.x) + a[1]);
        float e2 = 2.f * (bflo(xv.y) + a[2]);
        float e3 = 2.f * (bfhi(xv.y) + a[3]);
        u32 lo = (u32)f2bf(e0) | ((u32)f2bf(e1) << 16);
        u32 hi = (u32)f2bf(e2) | ((u32)f2bf(e3) << 16);
        *(uint2*)(Erm + p * 64 + sw) = make_uint2(lo, hi);
      }
    }
    __syncthreads();
    // m3: S^T += (I+S^T).E^T ; pack result into SOut (swizzled)
    {
      floatx4 acc[4];
#pragma unroll
      for (int i = 0; i < 4; ++i) acc[i] = (floatx4){0.f, 0.f, 0.f, 0.f};
#pragma unroll
      for (int kk = 0; kk < 2; ++kk) {
        int g = kk * 4 + kg;
        shortx8 af = *(const shortx8*)(Erm + qrow * 64 + ((g ^ qrow) & 7) * 8);
#pragma unroll
        for (int j2 = 0; j2 < 4; ++j2) {
          int p = j2 * 16 + lr;
          shortx8 bf = *(const shortx8*)(STb + p * 64 + ((g ^ p) & 7) * 8);
          acc[j2] = __builtin_amdgcn_mfma_f32_16x16x32_bf16(af, bf, acc[j2], 0, 0, 0);
        }
      }
#pragma unroll
      for (int j2 = 0; j2 < 4; ++j2) {
        int p = j2 * 16 + lr;
        floatx4 a = acc[j2];
        floatx4 s = sreg[j2];
        s[0] += a[0]; s[1] += a[1]; s[2] += a[2]; s[3] += a[3];
        sreg[j2] = s;
        u32 lo = (u32)f2bf(s[0]) | ((u32)f2bf(s[1]) << 16);
        u32 hi = (u32)f2bf(s[2]) | ((u32)f2bf(s[3]) << 16);
        *(uint2*)(SOut + p * 64 + (((q0 >> 3) ^ p) & 7) * 8 + (q0 & 7)) = make_uint2(lo, hi);
      }
    }
  }
  __syncthreads();
  // final writeout S_15
  {
    u16* Xprev = base + (size_t)15 * 4096;
    uint4 v0 = *(const uint4*)(SOut + wr * 64 + (((wg + 0) ^ wr) & 7) * 8);
    uint4 v1 = *(const uint4*)(SOut + wr * 64 + (((wg + 1) ^ wr) & 7) * 8);
    *(uint4*)(Xprev + wr * 64 + wg * 8) = v0;
    *(uint4*)(Xprev + wr * 64 + wg * 8 + 8) = v1;
  }
}

// ---------------- carry chain: z_{16(c+1)} = (I + S_15^{(c)}) z_{16c}; writes out[t=16c]
__global__ __launch_bounds__(64) void k_carry(const float* __restrict__ zin,
                                              const u16* __restrict__ R,
                                              float* __restrict__ out) {
  __shared__ __align__(16) u16 Ms[2][4096];
  int b = blockIdx.x, l = threadIdx.x;
  {
    const u16* M0 = R + ((size_t)(b * 512 + 15)) * 4096;
#pragma unroll
    for (int i = 0; i < 8; ++i) ((uint4*)Ms[0])[i * 64 + l] = ((const uint4*)M0)[i * 64 + l];
  }
  float cz = zin[(size_t)b * 512 * 64 + l];
  for (int c = 0; c < 32; ++c) {
    out[((size_t)(b * 512 + c * 16)) * 64 + l] = cz;
    uint4 nf0, nf1, nf2, nf3, nf4, nf5, nf6, nf7;
    if (c < 31) {
      const u16* Mn = R + ((size_t)(b * 512 + (c + 1) * 16 + 15)) * 4096;
      nf0 = ((const uint4*)Mn)[0 * 64 + l];
      nf1 = ((const uint4*)Mn)[1 * 64 + l];
      nf2 = ((const uint4*)Mn)[2 * 64 + l];
      nf3 = ((const uint4*)Mn)[3 * 64 + l];
      nf4 = ((const uint4*)Mn)[4 * 64 + l];
      nf5 = ((const uint4*)Mn)[5 * 64 + l];
      nf6 = ((const uint4*)Mn)[6 * 64 + l];
      nf7 = ((const uint4*)Mn)[7 * 64 + l];
    }
    const u16* M = Ms[c & 1];
    float a0 = 0.f, a1 = 0.f, a2 = 0.f, a3 = 0.f;
#pragma unroll
    for (int k = 0; k < 64; k += 4) {
      a0 = fmaf(bf1(M[(k + 0) * 64 + l]), __shfl(cz, k + 0), a0);
      a1 = fmaf(bf1(M[(k + 1) * 64 + l]), __shfl(cz, k + 1), a1);
      a2 = fmaf(bf1(M[(k + 2) * 64 + l]), __shfl(cz, k + 2), a2);
      a3 = fmaf(bf1(M[(k + 3) * 64 + l]), __shfl(cz, k + 3), a3);
    }
    cz += (a0 + a1) + (a2 + a3);
    if (c < 31) {
      uint4* d = (uint4*)Ms[(c + 1) & 1];
      d[0 * 64 + l] = nf0; d[1 * 64 + l] = nf1; d[2 * 64 + l] = nf2; d[3 * 64 + l] = nf3;
      d[4 * 64 + l] = nf4; d[5 * 64 + l] = nf5; d[6 * 64 + l] = nf6; d[7 * 64 + l] = nf7;
    }
  }
}

// ---------------- apply: z_{16c+j+1} = (I + S_j) z_{16c}, j = 0..14 (global-direct, L3-hot)
__global__ __launch_bounds__(256) void k_apply(const u16* __restrict__ R,
                                               float* __restrict__ out) {
  __shared__ float carr[64];
  int t = threadIdx.x, w = t >> 6, l = t & 63;
  int b = blockIdx.x >> 5, c = blockIdx.x & 31;
  const u16* Rb = R + ((size_t)(b * 512 + c * 16)) * 4096;
  if (t < 64) carr[t] = out[((size_t)(b * 512 + c * 16)) * 64 + t];
  __syncthreads();
  for (int j = w; j < 15; j += 4) {
    const u16* M = Rb + (size_t)j * 4096;
    float a0 = 0.f, a1 = 0.f, a2 = 0.f, a3 = 0.f;
#pragma unroll
    for (int k = 0; k < 64; k += 4) {
      a0 = fmaf(bf1(M[(k + 0) * 64 + l]), carr[k + 0], a0);
      a1 = fmaf(bf1(M[(k + 1) * 64 + l]), carr[k + 1], a1);
      a2 = fmaf(bf1(M[(k + 2) * 64 + l]), carr[k + 2], a2);
      a3 = fmaf(bf1(M[(k + 3) * 64 + l]), carr[k + 3], a3);
    }
    float zo = carr[l] + ((a0 + a1) + (a2 + a3));
    out[((size_t)(b * 512 + c * 16 + j + 1)) * 64 + l] = zo;
  }
}

extern "C" void kernel_launch(void* const* d_in, const int* in_sizes, int n_in,
                              void* d_out, int out_size, void* d_ws, size_t ws_size,
                              hipStream_t stream) {
  const float* z_input  = (const float*)d_in[0];
  const float* dt       = (const float*)d_in[1];
  const float* ln1_w    = (const float*)d_in[2];
  const float* ln1_b    = (const float*)d_in[3];
  const float* Lam_re   = (const float*)d_in[4];
  const float* Lam_im   = (const float*)d_in[5];
  const float* B_re     = (const float*)d_in[6];
  const float* B_im     = (const float*)d_in[7];
  const float* C_re     = (const float*)d_in[8];
  const float* C_im     = (const float*)d_in[9];
  const float* Dp       = (const float*)d_in[10];
  const float* log_step = (const float*)d_in[11];
  const float* ln2_w    = (const float*)d_in[12];
  const float* ln2_b    = (const float*)d_in[13];
  const float* ff_enc   = (const float*)d_in[14];
  const float* ff_dec   = (const float*)d_in[15];
  const float* toA_w1   = (const float*)d_in[16];
  const float* toA_b1   = (const float*)d_in[17];
  const float* toA_w2   = (const float*)d_in[18];
  const float* toA_b2   = (const float*)d_in[19];
  const float* mask_A   = (const float*)d_in[20];

  char* ws = (char*)d_ws;
  float* wLbar = (float*)(ws + 0);
  float* wBbr  = (float*)(ws + 2048);
  float* wBbi  = (float*)(ws + 67584);
  float* wCtr  = (float*)(ws + 133120);
  float* wCti  = (float*)(ws + 198656);
  float* wfx   = (float*)(ws + 264192);
  float* wx    = (float*)(ws + 4458496);
  float2* wbu  = (float2*)(ws + 8652800);
  u16* wh1     = (u16*)(ws + 25430016);   // [16384][128] bf16
  u16* w2T     = (u16*)(ws + 29624320);   // [4096][128] bf16
  u16* wX      = (u16*)(ws + 30672896);   // [16384][4096] bf16 (X, then ST in place)
  if (ws_size < 164890624ull) return;

  k_pre<<<2, 128, 0, stream>>>(Lam_re, Lam_im, log_step, B_re, B_im, C_re, C_im,
                               wLbar, wBbr, wBbi, wCtr, wCti);
  k_prew<<<64, 256, 0, stream>>>(toA_w2, w2T);
  for (int l = 0; l < 2; ++l) {
    const float* xin = (l == 0) ? z_input : wx;
    k_ln_bu<<<512, 256, 0, stream>>>(xin, ln1_w, ln1_b, wBbr, wBbi, wfx, wbu, l);
    k_scan<<<256, 256, 0, stream>>>(wbu, wLbar, l);
    k_yproj<<<512, 256, 0, stream>>>(wbu, wCtr, wCti, wfx, Dp, wx, l);
    k_ff<<<512, 256, 0, stream>>>(wx, ln2_w, ln2_b, ff_enc, ff_dec, l);
  }
  k_toa1<<<512, 256, 0, stream>>>(wx, toA_w1, toA_b1, wh1);
  k_gemm_mfma<<<dim3(32, 128), 256, 0, stream>>>(w2T, wh1, toA_b2, mask_A, dt, wX);
  k_chunk<<<1024, 256, 0, stream>>>(wX);
  k_carry<<<32, 64, 0, stream>>>(z_input, wX, (float*)d_out);
  k_apply<<<1024, 256, 0, stream>>>(wX, (float*)d_out);
}

// Round 7
// 386.976 us; speedup vs baseline: 2.5001x; 1.0256x over previous
//
#include <hip/hip_runtime.h>

#define DI __device__ __forceinline__

typedef unsigned short u16;
typedef unsigned int u32;
typedef __attribute__((ext_vector_type(8))) short shortx8;
typedef __attribute__((ext_vector_type(4))) float floatx4;

DI float u2f(u32 x) { union { u32 u; float f; } v; v.u = x; return v.f; }
DI u32 f2u(float x) { union { u32 u; float f; } v; v.f = x; return v.u; }
DI float bflo(u32 w) { return u2f(w << 16); }
DI float bfhi(u32 w) { return u2f(w & 0xffff0000u); }
DI float bf1(u16 w) { return u2f(((u32)w) << 16); }
DI u16 f2bf(float f) {  // RNE
  u32 u = f2u(f);
  u32 r = (u + 0x7fffu + ((u >> 16) & 1u)) >> 16;
  return (u16)r;
}

DI float wsum64(float v) {
  v += __shfl_xor(v, 32);
  v += __shfl_xor(v, 16);
  v += __shfl_xor(v, 8);
  v += __shfl_xor(v, 4);
  v += __shfl_xor(v, 2);
  v += __shfl_xor(v, 1);
  return v;
}

DI float gelu_ex(float y) { return 0.5f * y * (1.0f + erff(y * 0.7071067811865476f)); }
DI float softplus_ex(float x) { return x > 0.f ? x + log1pf(expf(-x)) : log1pf(expf(x)); }

// ---------------- fused precompute: blocks 0..63 transpose w2; blocks 64..65 Lbar/Bbar/C
__global__ __launch_bounds__(256) void k_pre2(
    const float* __restrict__ Lam_re, const float* __restrict__ Lam_im,
    const float* __restrict__ log_step,
    const float* __restrict__ B_re, const float* __restrict__ B_im,
    const float* __restrict__ C_re, const float* __restrict__ C_im,
    const float* __restrict__ w2,
    float* __restrict__ wLbar, float* __restrict__ wBbr, float* __restrict__ wBbi,
    float* __restrict__ wCtr, float* __restrict__ wCti, u16* __restrict__ w2T) {
  if (blockIdx.x < 64) {
    __shared__ float s[128][65];
    int t = threadIdx.x;
    int n0 = blockIdx.x * 64;
    for (int i = 0; i < 32; ++i) {
      int e = i * 256 + t;
      int k = e >> 6, n = e & 63;
      s[k][n] = w2[(size_t)k * 4096 + n0 + n];
    }
    __syncthreads();
    for (int i = 0; i < 16; ++i) {
      int e = i * 256 + t;
      int n = e >> 6, kp = e & 63;
      u32 pk = (u32)f2bf(s[kp * 2][n]) | ((u32)f2bf(s[kp * 2 + 1][n]) << 16);
      ((u32*)w2T)[(size_t)(n0 + n) * 64 + kp] = pk;
    }
  } else {
    int l = blockIdx.x - 64;
    int p = threadIdx.x;
    if (p < 128) {
      int idx = l * 128 + p;
      float step = expf(log_step[idx]);
      float lre = -expf(Lam_re[idx]);
      float lim = Lam_im[idx];
      float er = expf(lre * step);
      float Lr = er * cosf(lim * step);
      float Li = er * sinf(lim * step);
      wLbar[idx * 2] = Lr;
      wLbar[idx * 2 + 1] = Li;
      float inv = 1.0f / (lre * lre + lim * lim);
      float nr = Lr - 1.0f, ni = Li;
      float qr = (nr * lre + ni * lim) * inv;
      float qi = (ni * lre - nr * lim) * inv;
      for (int h = 0; h < 64; ++h) {
        float br = B_re[idx * 64 + h], bim = B_im[idx * 64 + h];
        wBbr[(l * 64 + h) * 128 + p] = qr * br - qi * bim;
        wBbi[(l * 64 + h) * 128 + p] = qr * bim + qi * br;
        wCtr[idx * 64 + h] = C_re[(l * 64 + h) * 128 + p];
        wCti[idx * 64 + h] = C_im[(l * 64 + h) * 128 + p];
      }
    }
  }
}

// ---------------- LN1 + Bu = einsum('ph,blh->blp')
__global__ __launch_bounds__(256) void k_ln_bu(
    const float* __restrict__ xin, const float* __restrict__ lnw, const float* __restrict__ lnb,
    const float* __restrict__ wBbr, const float* __restrict__ wBbi,
    float* __restrict__ fxg, float2* __restrict__ bu, int layer) {
  __shared__ float sbr[64 * 128];
  __shared__ float sbi[64 * 128];
  int t = threadIdx.x, w = t >> 6, lane = t & 63;
  {
    const float* br = wBbr + (size_t)layer * 8192;
    const float* bi = wBbi + (size_t)layer * 8192;
    for (int e = t; e < 8192; e += 256) { sbr[e] = br[e]; sbi[e] = bi[e]; }
  }
  float wv = lnw[layer * 64 + lane], bv = lnb[layer * 64 + lane];
  __syncthreads();
  int row0 = blockIdx.x * 32 + w * 8;
  float fxv[8];
#pragma unroll
  for (int rr = 0; rr < 8; ++rr) {
    size_t r = row0 + rr;
    float x = xin[r * 64 + lane];
    float mu = wsum64(x) * 0.015625f;
    float d = x - mu;
    float var = wsum64(d * d) * 0.015625f;
    float fx = d * rsqrtf(var + 1e-5f) * wv + bv;
    fxv[rr] = fx;
    fxg[r * 64 + lane] = fx;
  }
  float ar0[8] = {}, ai0[8] = {}, ar1[8] = {}, ai1[8] = {};
  for (int h = 0; h < 64; ++h) {
    float b0r = sbr[h * 128 + lane], b0i = sbi[h * 128 + lane];
    float b1r = sbr[h * 128 + lane + 64], b1i = sbi[h * 128 + lane + 64];
#pragma unroll
    for (int rr = 0; rr < 8; ++rr) {
      float f = __shfl(fxv[rr], h);
      ar0[rr] = fmaf(b0r, f, ar0[rr]);
      ai0[rr] = fmaf(b0i, f, ai0[rr]);
      ar1[rr] = fmaf(b1r, f, ar1[rr]);
      ai1[rr] = fmaf(b1i, f, ai1[rr]);
    }
  }
#pragma unroll
  for (int rr = 0; rr < 8; ++rr) {
    size_t r = row0 + rr;
    bu[r * 128 + lane] = make_float2(ar0[rr], ai0[rr]);
    bu[r * 128 + lane + 64] = make_float2(ar1[rr], ai1[rr]);
  }
}

// ---------------- diagonal complex inclusive scan over L, chunked 3-phase (in place)
__global__ __launch_bounds__(256) void k_scan(float2* __restrict__ bu,
                                              const float* __restrict__ wLbar, int layer) {
  __shared__ float2 carry[16][17];
  int t = threadIdx.x;
  int ck = t >> 4, chain = t & 15;
  int b = blockIdx.x >> 3;
  int p = (blockIdx.x & 7) * 16 + chain;
  float Lr = wLbar[(layer * 128 + p) * 2];
  float Li = wLbar[(layer * 128 + p) * 2 + 1];
  float2* ptr = bu + ((size_t)b * 512 * 128 + p);
  int l0 = ck * 32;
  float xr = 0.f, xi = 0.f;
#pragma unroll 4
  for (int i = 0; i < 32; ++i) {
    float2 v = ptr[(size_t)(l0 + i) * 128];
    float nr = fmaf(Lr, xr, fmaf(-Li, xi, v.x));
    float ni = fmaf(Lr, xi, fmaf(Li, xr, v.y));
    xr = nr; xi = ni;
  }
  carry[chain][ck] = make_float2(xr, xi);
  __syncthreads();
  if (t < 16) {
    float ar = Lr, ai = Li;
#pragma unroll
    for (int s = 0; s < 5; ++s) {
      float nr = ar * ar - ai * ai;
      float ni = 2.f * ar * ai;
      ar = nr; ai = ni;
    }
    float cr = 0.f, ci2 = 0.f;
#pragma unroll
    for (int m = 0; m < 16; ++m) {
      float2 loc = carry[t][m];
      carry[t][m] = make_float2(cr, ci2);
      float nr = fmaf(ar, cr, fmaf(-ai, ci2, loc.x));
      float ni = fmaf(ar, ci2, fmaf(ai, cr, loc.y));
      cr = nr; ci2 = ni;
    }
  }
  __syncthreads();
  float2 c0 = carry[chain][ck];
  xr = c0.x; xi = c0.y;
#pragma unroll 4
  for (int i = 0; i < 32; ++i) {
    float2 v = ptr[(size_t)(l0 + i) * 128];
    float nr = fmaf(Lr, xr, fmaf(-Li, xi, v.x));
    float ni = fmaf(Lr, xi, fmaf(Li, xr, v.y));
    xr = nr; xi = ni;
    ptr[(size_t)(l0 + i) * 128] = make_float2(xr, xi);
  }
}

// ---------------- fused y-projection + GLU FFN (+ toa1 for layer 1)
// phase A: y = 2Re(C xs) + D*u ; x = gelu(y)+fx   (regs)
// phase B: LN2(x), GLU FFN, x2 = o + fx2           (regs; layer0 -> write wx)
// phase C (layer1): h1 = softplus(x2 @ w1 + b1) -> bf16 packed
__global__ __launch_bounds__(256) void k_yff(
    const float2* __restrict__ xs, const float* __restrict__ wCtr, const float* __restrict__ wCti,
    const float* __restrict__ fxg, const float* __restrict__ Dp,
    const float* __restrict__ ln2w, const float* __restrict__ ln2b,
    const float* __restrict__ encw, const float* __restrict__ decw,
    const float* __restrict__ w1, const float* __restrict__ b1,
    float* __restrict__ xout, u16* __restrict__ h1out, int layer) {
  __shared__ union {
    struct { float ctr[4096]; float cti[4096]; float2 xsh[4][8][64]; } a;
    struct { float enc[8192]; float dec[4096]; } b;
    struct { float w1s[8192]; } c;
  } sm;
  int t = threadIdx.x, w = t >> 6, lane = t & 63;
  int row0 = blockIdx.x * 32 + w * 8;
  // ---- phase A: yproj
  float acc[8] = {};
  for (int ph = 0; ph < 2; ++ph) {
    __syncthreads();
    {
      const float* sr = wCtr + ((size_t)layer * 128 + ph * 64) * 64;
      const float* si = wCti + ((size_t)layer * 128 + ph * 64) * 64;
      for (int e = t; e < 4096; e += 256) { sm.a.ctr[e] = sr[e]; sm.a.cti[e] = si[e]; }
    }
#pragma unroll
    for (int rr = 0; rr < 8; ++rr) {
      size_t r = row0 + rr;
      sm.a.xsh[w][rr][lane] = xs[r * 128 + ph * 64 + lane];
    }
    __syncthreads();
    for (int p = 0; p < 64; ++p) {
      float cr = sm.a.ctr[p * 64 + lane];
      float ci = sm.a.cti[p * 64 + lane];
#pragma unroll
      for (int rr = 0; rr < 8; ++rr) {
        float2 xv = sm.a.xsh[w][rr][p];
        acc[rr] = fmaf(cr, xv.x, fmaf(-ci, xv.y, acc[rr]));
      }
    }
  }
  float Dv = Dp[layer * 64 + lane];
  float xv[8];
#pragma unroll
  for (int rr = 0; rr < 8; ++rr) {
    size_t r = row0 + rr;
    float u = fxg[r * 64 + lane];
    float y = 2.f * acc[rr] + Dv * u;
    xv[rr] = gelu_ex(y) + u;
  }
  // ---- phase B: ff
  __syncthreads();  // done reading sm.a
  {
    const float* e = encw + (size_t)layer * 8192;
    for (int i = t; i < 8192; i += 256) sm.b.enc[i] = e[i];
    const float* d = decw + (size_t)layer * 4096;
    for (int i = t; i < 4096; i += 256) sm.b.dec[i] = d[i];
  }
  float wv = ln2w[layer * 64 + lane], bv = ln2b[layer * 64 + lane];
  __syncthreads();
  float fx2v[8];
#pragma unroll
  for (int rr = 0; rr < 8; ++rr) {
    float x = xv[rr];
    float mu = wsum64(x) * 0.015625f;
    float d = x - mu;
    float var = wsum64(d * d) * 0.015625f;
    fx2v[rr] = d * rsqrtf(var + 1e-5f) * wv + bv;
  }
  float h0[8] = {}, h1v[8] = {};
  for (int h = 0; h < 64; ++h) {
    float e0 = sm.b.enc[h * 128 + lane], e1 = sm.b.enc[h * 128 + lane + 64];
#pragma unroll
    for (int rr = 0; rr < 8; ++rr) {
      float f = __shfl(fx2v[rr], h);
      h0[rr] = fmaf(e0, f, h0[rr]);
      h1v[rr] = fmaf(e1, f, h1v[rr]);
    }
  }
  float gv[8];
#pragma unroll
  for (int rr = 0; rr < 8; ++rr) gv[rr] = h0[rr] * gelu_ex(h1v[rr]);
  float x2[8];
  {
    float o[8] = {};
    for (int j = 0; j < 64; ++j) {
      float dv = sm.b.dec[j * 64 + lane];
#pragma unroll
      for (int rr = 0; rr < 8; ++rr) {
        float gj = __shfl(gv[rr], j);
        o[rr] = fmaf(dv, gj, o[rr]);
      }
    }
#pragma unroll
    for (int rr = 0; rr < 8; ++rr) x2[rr] = o[rr] + fx2v[rr];
  }
  if (layer == 0) {
#pragma unroll
    for (int rr = 0; rr < 8; ++rr) xout[(size_t)(row0 + rr) * 64 + lane] = x2[rr];
    return;
  }
  // ---- phase C: toa1 (layer 1 only)
  __syncthreads();  // done reading sm.b
  for (int i = t; i < 8192; i += 256) sm.c.w1s[i] = w1[i];
  float bb0 = b1[lane], bb1 = b1[lane + 64];
  __syncthreads();
  float a0[8] = {}, a1[8] = {};
  for (int h = 0; h < 64; ++h) {
    float e0 = sm.c.w1s[h * 128 + lane], e1 = sm.c.w1s[h * 128 + lane + 64];
#pragma unroll
    for (int rr = 0; rr < 8; ++rr) {
      float f = __shfl(x2[rr], h);
      a0[rr] = fmaf(e0, f, a0[rr]);
      a1[rr] = fmaf(e1, f, a1[rr]);
    }
  }
#pragma unroll
  for (int rr = 0; rr < 8; ++rr) {
    size_t r = row0 + rr;
    float v0 = softplus_ex(a0[rr] + bb0);
    float v1 = softplus_ex(a1[rr] + bb1);
    int sl = (2 * lane) & 63;
    float ea = __shfl(v0, sl), eb = __shfl(v1, sl);
    float oa = __shfl(v0, sl + 1), ob = __shfl(v1, sl + 1);
    float lo = (lane < 32) ? ea : eb;
    float hi = (lane < 32) ? oa : ob;
    ((u32*)h1out)[r * 64 + lane] = (u32)f2bf(lo) | ((u32)f2bf(hi) << 16);
  }
}

// ---------------- MFMA big GEMM: X[m][n] = 0.5*dt[m]*(h1@w2 + b2)[m][n]*mask[n] -> bf16
__global__ __launch_bounds__(256) void k_gemm_mfma(
    const u16* __restrict__ w2T, const u16* __restrict__ h1,
    const float* __restrict__ b2, const float* __restrict__ mask,
    const float* __restrict__ dt, u16* __restrict__ Xout) {
  __shared__ __align__(16) u16 As[128 * 128];
  __shared__ __align__(16) u16 Bs[128 * 128];
  int t = threadIdx.x;
  int bn = blockIdx.x;
  int bm = blockIdx.y;
  {
    const u16* srcA = w2T + (size_t)(bn * 128) * 128;
    const u16* srcB = h1 + (size_t)(bm * 128) * 128;
#pragma unroll
    for (int i = 0; i < 8; ++i) {
      int r = i * 16 + (t >> 4);
      int gs = t & 15;
      int gsw = (gs & 8) | ((gs ^ r) & 7);
      uint4 va = *(const uint4*)(srcA + r * 128 + gs * 8);
      *(uint4*)(As + r * 128 + gsw * 8) = va;
      uint4 vb = *(const uint4*)(srcB + r * 128 + gs * 8);
      *(uint4*)(Bs + r * 128 + gsw * 8) = vb;
    }
  }
  __syncthreads();
  int w = t >> 6, l = t & 63;
  int n0 = (w & 1) * 64, m0 = (w >> 1) * 64;
  int lr = l & 15, kg = l >> 4;
  floatx4 acc[4][4];
#pragma unroll
  for (int i = 0; i < 4; ++i)
#pragma unroll
    for (int j = 0; j < 4; ++j) acc[i][j] = (floatx4){0.f, 0.f, 0.f, 0.f};
#pragma unroll
  for (int kk = 0; kk < 4; ++kk) {
    int g = kk * 4 + kg;
    shortx8 af[4], bf[4];
#pragma unroll
    for (int ni = 0; ni < 4; ++ni) {
      int r = n0 + ni * 16 + lr;
      int gsw = (g & 8) | ((g ^ r) & 7);
      af[ni] = *(const shortx8*)(As + r * 128 + gsw * 8);
    }
#pragma unroll
    for (int mi = 0; mi < 4; ++mi) {
      int r = m0 + mi * 16 + lr;
      int gsw = (g & 8) | ((g ^ r) & 7);
      bf[mi] = *(const shortx8*)(Bs + r * 128 + gsw * 8);
    }
#pragma unroll
    for (int ni = 0; ni < 4; ++ni)
#pragma unroll
      for (int mi = 0; mi < 4; ++mi)
        acc[ni][mi] = __builtin_amdgcn_mfma_f32_16x16x32_bf16(af[ni], bf[mi], acc[ni][mi], 0, 0, 0);
  }
  __syncthreads();
  int q = (l >> 4) * 4;
#pragma unroll
  for (int mi = 0; mi < 4; ++mi) {
    int ml = m0 + mi * 16 + lr;
    int m = bm * 128 + ml;
    float dv = 0.5f * dt[m];
#pragma unroll
    for (int ni = 0; ni < 4; ++ni) {
      int nl = n0 + ni * 16 + q;
      int n = bn * 128 + nl;
      float4 bb = *(const float4*)&b2[n];
      float4 mk = *(const float4*)&mask[n];
      floatx4 a = acc[ni][mi];
      float x0 = dv * (a[0] + bb.x) * mk.x;
      float x1 = dv * (a[1] + bb.y) * mk.y;
      float x2 = dv * (a[2] + bb.z) * mk.z;
      float x3 = dv * (a[3] + bb.w) * mk.w;
      u32 lo = (u32)f2bf(x0) | ((u32)f2bf(x1) << 16);
      u32 hi = (u32)f2bf(x2) | ((u32)f2bf(x3) << 16);
      int g = nl >> 3;
      int gsw = (g & 8) | ((g ^ ml) & 7);
      *(uint2*)(As + ml * 128 + gsw * 8 + (nl & 7)) = make_uint2(lo, hi);
    }
  }
  __syncthreads();
  int seg = t & 7;
#pragma unroll
  for (int pp = 0; pp < 4; ++pp) {
    int r = pp * 32 + (t >> 3);
#pragma unroll
    for (int ii = 0; ii < 2; ++ii) {
      int g = seg * 2 + ii;
      int gsw = (g & 8) | ((g ^ r) & 7);
      uint4 v = *(const uint4*)(As + r * 128 + gsw * 8);
      *(uint4*)&Xout[(size_t)(bm * 128 + r) * 4096 + bn * 128 + g * 8] = v;
    }
  }
}

// ---------------- fused chunk kernel: A_t = I + 2(X+X^2); R_j = A_{t0+j}...A_{t0};
// stores S_j = (R_j - I) bf16 ROW-major (transposed scatter into SOut) IN PLACE over X_t.
__global__ __launch_bounds__(256, 4) void k_chunk(u16* __restrict__ Xg) {
  __shared__ __align__(16) u16 Xrm[4096];
  __shared__ __align__(16) u16 XTrm[4096];
  __shared__ __align__(16) u16 Erm[4096];
  __shared__ __align__(16) u16 STb[4096];
  __shared__ __align__(16) u16 SOut[4096];
  int t = threadIdx.x, w = t >> 6, l = t & 63;
  int lr = l & 15, kg = l >> 4;
  int b = blockIdx.x >> 5, c = blockIdx.x & 31;
  u16* base = Xg + ((size_t)(b * 512 + c * 16)) * 4096;
  floatx4 sreg[4];
#pragma unroll
  for (int i = 0; i < 4; ++i) sreg[i] = (floatx4){0.f, 0.f, 0.f, 0.f};
  int r0 = (t >> 3) * 2, c0 = (t & 7) * 8, g0 = t & 7;
  int cw = t >> 3;
  uint4 pf0 = *(const uint4*)(base + r0 * 64 + c0);
  uint4 pf1 = *(const uint4*)(base + (r0 + 1) * 64 + c0);
  int q0 = w * 16 + kg * 4;
  int qrow = w * 16 + lr;
  int wr = t >> 2, wg = (t & 3) * 2;
  for (int j = 0; j < 16; ++j) {
    __syncthreads();
    if (j > 0) {
      u16* Xprev = base + (size_t)(j - 1) * 4096;
      uint4 v0 = *(const uint4*)(SOut + wr * 64 + (((wg + 0) ^ wr) & 7) * 8);
      uint4 v1 = *(const uint4*)(SOut + wr * 64 + (((wg + 1) ^ wr) & 7) * 8);
      *(uint4*)(Xprev + wr * 64 + wg * 8) = v0;
      *(uint4*)(Xprev + wr * 64 + wg * 8 + 8) = v1;
    }
    *(uint4*)(Xrm + r0 * 64 + ((g0 ^ r0) & 7) * 8) = pf0;
    *(uint4*)(Xrm + (r0 + 1) * 64 + ((g0 ^ (r0 + 1)) & 7) * 8) = pf1;
    {
      const u16* a = (const u16*)&pf0;
      const u16* bq = (const u16*)&pf1;
#pragma unroll
      for (int i = 0; i < 8; ++i) {
        int ci = (i + t) & 7;
        int cc = c0 + ci;
        u32 val = (u32)a[ci] | ((u32)bq[ci] << 16);
        ((u32*)XTrm)[cc * 32 + (((cw >> 2) ^ cc) & 7) * 4 + (cw & 3)] = val;
      }
    }
#pragma unroll
    for (int j2 = 0; j2 < 4; ++j2) {
      int p = j2 * 16 + lr;
      floatx4 s = sreg[j2];
      float v0 = s[0] + ((p == q0 + 0) ? 1.f : 0.f);
      float v1 = s[1] + ((p == q0 + 1) ? 1.f : 0.f);
      float v2 = s[2] + ((p == q0 + 2) ? 1.f : 0.f);
      float v3 = s[3] + ((p == q0 + 3) ? 1.f : 0.f);
      u32 lo = (u32)f2bf(v0) | ((u32)f2bf(v1) << 16);
      u32 hi = (u32)f2bf(v2) | ((u32)f2bf(v3) << 16);
      *(uint2*)(STb + p * 64 + (((q0 >> 3) ^ p) & 7) * 8 + (q0 & 7)) = make_uint2(lo, hi);
    }
    if (j < 15) {
      const u16* nx = base + (size_t)(j + 1) * 4096;
      pf0 = *(const uint4*)(nx + r0 * 64 + c0);
      pf1 = *(const uint4*)(nx + (r0 + 1) * 64 + c0);
    }
    __syncthreads();
    shortx8 afx0 = *(const shortx8*)(XTrm + qrow * 64 + ((kg ^ qrow) & 7) * 8);
    shortx8 afx1 = *(const shortx8*)(XTrm + qrow * 64 + (((4 + kg) ^ qrow) & 7) * 8);
    {
      floatx4 acc[4];
#pragma unroll
      for (int i = 0; i < 4; ++i) acc[i] = (floatx4){0.f, 0.f, 0.f, 0.f};
#pragma unroll
      for (int kk = 0; kk < 2; ++kk) {
        int g = kk * 4 + kg;
        shortx8 af = kk ? afx1 : afx0;
#pragma unroll
        for (int j2 = 0; j2 < 4; ++j2) {
          int p = j2 * 16 + lr;
          shortx8 bf = *(const shortx8*)(Xrm + p * 64 + ((g ^ p) & 7) * 8);
          acc[j2] = __builtin_amdgcn_mfma_f32_16x16x32_bf16(af, bf, acc[j2], 0, 0, 0);
        }
      }
#pragma unroll
      for (int j2 = 0; j2 < 4; ++j2) {
        int p = j2 * 16 + lr;
        int sw = (((q0 >> 3) ^ p) & 7) * 8 + (q0 & 7);
        uint2 xv = *(const uint2*)(Xrm + p * 64 + sw);
        floatx4 a = acc[j2];
        float e0 = 2.f * (bflo(xv.x) + a[0]);
        float e1 = 2.f * (bfhi(xv.x) + a[1]);
        float e2 = 2.f * (bflo(xv.y) + a[2]);
        float e3 = 2.f * (bfhi(xv.y) + a[3]);
        u32 lo = (u32)f2bf(e0) | ((u32)f2bf(e1) << 16);
        u32 hi = (u32)f2bf(e2) | ((u32)f2bf(e3) << 16);
        *(uint2*)(Erm + p * 64 + sw) = make_uint2(lo, hi);
      }
    }
    __syncthreads();
    {
      floatx4 acc[4];
#pragma unroll
      for (int i = 0; i < 4; ++i) acc[i] = (floatx4){0.f, 0.f, 0.f, 0.f};
#pragma unroll
      for (int kk = 0; kk < 2; ++kk) {
        int g = kk * 4 + kg;
        shortx8 af = *(const shortx8*)(Erm + qrow * 64 + ((g ^ qrow) & 7) * 8);
#pragma unroll
        for (int j2 = 0; j2 < 4; ++j2) {
          int p = j2 * 16 + lr;
          shortx8 bf = *(const shortx8*)(STb + p * 64 + ((g ^ p) & 7) * 8);
          acc[j2] = __builtin_amdgcn_mfma_f32_16x16x32_bf16(af, bf, acc[j2], 0, 0, 0);
        }
      }
#pragma unroll
      for (int j2 = 0; j2 < 4; ++j2) {
        int p = j2 * 16 + lr;
        floatx4 a = acc[j2];
        floatx4 s = sreg[j2];
        s[0] += a[0]; s[1] += a[1]; s[2] += a[2]; s[3] += a[3];
        sreg[j2] = s;
        // transposed scatter: SOut[r2][p] = S[r2][p]  (row-major S)
#pragma unroll
        for (int i = 0; i < 4; ++i) {
          int r2 = q0 + i;
          SOut[r2 * 64 + (((p >> 3) ^ r2) & 7) * 8 + (p & 7)] = f2bf(s[i]);
        }
      }
    }
  }
  __syncthreads();
  {
    u16* Xprev = base + (size_t)15 * 4096;
    uint4 v0 = *(const uint4*)(SOut + wr * 64 + (((wg + 0) ^ wr) & 7) * 8);
    uint4 v1 = *(const uint4*)(SOut + wr * 64 + (((wg + 1) ^ wr) & 7) * 8);
    *(uint4*)(Xprev + wr * 64 + wg * 8) = v0;
    *(uint4*)(Xprev + wr * 64 + wg * 8 + 8) = v1;
  }
}

// ---------------- carry chain: z_{16(c+1)} = (I + S_15^{(c)}) z_{16c}; row-major S
__global__ __launch_bounds__(64) void k_carry(const float* __restrict__ zin,
                                              const u16* __restrict__ R,
                                              float* __restrict__ out) {
  int b = blockIdx.x, l = threadIdx.x;
  uint4 cf[8], nf[8];
  {
    const uint4* M0 = (const uint4*)(R + ((size_t)(b * 512 + 15)) * 4096 + l * 64);
#pragma unroll
    for (int g = 0; g < 8; ++g) cf[g] = M0[g];
  }
  float cz = zin[(size_t)b * 512 * 64 + l];
  for (int c = 0; c < 32; ++c) {
    out[((size_t)(b * 512 + c * 16)) * 64 + l] = cz;
    if (c < 31) {
      const uint4* Mn = (const uint4*)(R + ((size_t)(b * 512 + (c + 1) * 16 + 15)) * 4096 + l * 64);
#pragma unroll
      for (int g = 0; g < 8; ++g) nf[g] = Mn[g];
    }
    float a0 = 0.f, a1 = 0.f, a2 = 0.f, a3 = 0.f;
#pragma unroll
    for (int g = 0; g < 8; ++g) {
      uint4 v = cf[g];
      int k = g * 8;
      a0 = fmaf(bflo(v.x), __shfl(cz, k + 0), a0);
      a1 = fmaf(bfhi(v.x), __shfl(cz, k + 1), a1);
      a2 = fmaf(bflo(v.y), __shfl(cz, k + 2), a2);
      a3 = fmaf(bfhi(v.y), __shfl(cz, k + 3), a3);
      a0 = fmaf(bflo(v.z), __shfl(cz, k + 4), a0);
      a1 = fmaf(bfhi(v.z), __shfl(cz, k + 5), a1);
      a2 = fmaf(bflo(v.w), __shfl(cz, k + 6), a2);
      a3 = fmaf(bfhi(v.w), __shfl(cz, k + 7), a3);
    }
    cz += (a0 + a1) + (a2 + a3);
    if (c < 31) {
#pragma unroll
      for (int g = 0; g < 8; ++g) cf[g] = nf[g];
    }
  }
}

// ---------------- apply: z_{16c+j+1} = (I + S_j) z_{16c}; row-major S, vectorized rows
__global__ __launch_bounds__(256) void k_apply(const u16* __restrict__ R,
                                               float* __restrict__ out) {
  __shared__ float carr[64];
  int t = threadIdx.x, w = t >> 6, l = t & 63;
  int b = blockIdx.x >> 5, c = blockIdx.x & 31;
  const u16* Rb = R + ((size_t)(b * 512 + c * 16)) * 4096;
  if (t < 64) carr[t] = out[((size_t)(b * 512 + c * 16)) * 64 + t];
  __syncthreads();
  float zl = carr[l];
  for (int j = w; j < 15; j += 4) {
    const uint4* M = (const uint4*)(Rb + (size_t)j * 4096 + l * 64);
    float a0 = 0.f, a1 = 0.f, a2 = 0.f, a3 = 0.f;
#pragma unroll
    for (int g = 0; g < 8; ++g) {
      uint4 v = M[g];
      const float* zb = &carr[g * 8];
      a0 = fmaf(bflo(v.x), zb[0], a0);
      a1 = fmaf(bfhi(v.x), zb[1], a1);
      a2 = fmaf(bflo(v.y), zb[2], a2);
      a3 = fmaf(bfhi(v.y), zb[3], a3);
      a0 = fmaf(bflo(v.z), zb[4], a0);
      a1 = fmaf(bfhi(v.z), zb[5], a1);
      a2 = fmaf(bflo(v.w), zb[6], a2);
      a3 = fmaf(bfhi(v.w), zb[7], a3);
    }
    out[((size_t)(b * 512 + c * 16 + j + 1)) * 64 + l] = zl + ((a0 + a1) + (a2 + a3));
  }
}

extern "C" void kernel_launch(void* const* d_in, const int* in_sizes, int n_in,
                              void* d_out, int out_size, void* d_ws, size_t ws_size,
                              hipStream_t stream) {
  const float* z_input  = (const float*)d_in[0];
  const float* dt       = (const float*)d_in[1];
  const float* ln1_w    = (const float*)d_in[2];
  const float* ln1_b    = (const float*)d_in[3];
  const float* Lam_re   = (const float*)d_in[4];
  const float* Lam_im   = (const float*)d_in[5];
  const float* B_re     = (const float*)d_in[6];
  const float* B_im     = (const float*)d_in[7];
  const float* C_re     = (const float*)d_in[8];
  const float* C_im     = (const float*)d_in[9];
  const float* Dp       = (const float*)d_in[10];
  const float* log_step = (const float*)d_in[11];
  const float* ln2_w    = (const float*)d_in[12];
  const float* ln2_b    = (const float*)d_in[13];
  const float* ff_enc   = (const float*)d_in[14];
  const float* ff_dec   = (const float*)d_in[15];
  const float* toA_w1   = (const float*)d_in[16];
  const float* toA_b1   = (const float*)d_in[17];
  const float* toA_w2   = (const float*)d_in[18];
  const float* toA_b2   = (const float*)d_in[19];
  const float* mask_A   = (const float*)d_in[20];

  char* ws = (char*)d_ws;
  float* wLbar = (float*)(ws + 0);
  float* wBbr  = (float*)(ws + 2048);
  float* wBbi  = (float*)(ws + 67584);
  float* wCtr  = (float*)(ws + 133120);
  float* wCti  = (float*)(ws + 198656);
  float* wfx   = (float*)(ws + 264192);
  float* wx    = (float*)(ws + 4458496);
  float2* wbu  = (float2*)(ws + 8652800);
  u16* wh1     = (u16*)(ws + 25430016);   // [16384][128] bf16
  u16* w2T     = (u16*)(ws + 29624320);   // [4096][128] bf16
  u16* wX      = (u16*)(ws + 30672896);   // [16384][4096] bf16 (X, then S in place)
  if (ws_size < 164890624ull) return;

  k_pre2<<<66, 256, 0, stream>>>(Lam_re, Lam_im, log_step, B_re, B_im, C_re, C_im,
                                 toA_w2, wLbar, wBbr, wBbi, wCtr, wCti, w2T);
  for (int l = 0; l < 2; ++l) {
    const float* xin = (l == 0) ? z_input : wx;
    k_ln_bu<<<512, 256, 0, stream>>>(xin, ln1_w, ln1_b, wBbr, wBbi, wfx, wbu, l);
    k_scan<<<256, 256, 0, stream>>>(wbu, wLbar, l);
    k_yff<<<512, 256, 0, stream>>>(wbu, wCtr, wCti, wfx, Dp, ln2_w, ln2_b, ff_enc, ff_dec,
                                   toA_w1, toA_b1, wx, wh1, l);
  }
  k_gemm_mfma<<<dim3(32, 128), 256, 0, stream>>>(w2T, wh1, toA_b2, mask_A, dt, wX);
  k_chunk<<<1024, 256, 0, stream>>>(wX);
  k_carry<<<32, 64, 0, stream>>>(z_input, wX, (float*)d_out);
  k_apply<<<1024, 256, 0, stream>>>(wX, (float*)d_out);
}